// Round 7
// baseline (293.701 us; speedup 1.0000x reference)
//
#include <hip/hip_runtime.h>
#include <hip/hip_bf16.h>
#include <stdint.h>

typedef __bf16 bf16x8 __attribute__((ext_vector_type(8)));
typedef short short8v __attribute__((ext_vector_type(8)));
typedef float f32x4 __attribute__((ext_vector_type(4)));

#define B_     128
#define T_     448
#define NS     384
#define NH     6
#define HD     64
#define VOCAB_ 10000
#define NOUT   22020096   // B_*T_*NS

// ws layout (ushort element offsets). Tables are bf16.
// qtab: (emb@Wq^T + bq) * scale * log2(e)  (pre-scaled for exp2 softmax)
// ktab: (emb@Wk^T) * scale        (pre-scaled; gather multiplies by 1/scale)
// vtab: (emb@Wv^T + bv)           (unscaled)
#define OFF_WQ   0
#define OFF_WK   147456
#define OFF_WV   294912
#define OFF_WO   442368
#define OFF_QTAB 589824
#define OFF_KTAB 4429824
#define OFF_VTAB 8269824
// end: 12109824 ushorts = 24.2 MB

#define NATT2  896                // (b, qtile) blocks: 128*7
#define NGAT   10752              // gather blocks (2752512 chunks / 256)
#define NFUSE  (NATT2 + NGAT)     // 11648

__device__ __forceinline__ unsigned short f2bf(float f) {
    union { __bf16 h; unsigned short u; } v;
    v.h = (__bf16)f;
    return v.u;
}
__device__ __forceinline__ float bf2f(unsigned short u) {
    union { uint32_t u; float f; } v; v.u = (uint32_t)u << 16;
    return v.f;
}

// ---------------- kernel 0: f32 -> bf16 weights only ----------------------
__global__ __launch_bounds__(256) void k_prep(
    const float* __restrict__ Wq, const float* __restrict__ Wk,
    const float* __restrict__ Wv, const float* __restrict__ Wo,
    unsigned short* __restrict__ ws)
{
    const float* srcs[4] = {Wq, Wk, Wv, Wo};
    const int seg = blockIdx.y;
    int i = (blockIdx.x * 256 + threadIdx.x) * 4;
    if (i >= 147456) return;
    float4 v = *(const float4*)(srcs[seg] + i);
    ushort4 o;
    o.x = f2bf(v.x); o.y = f2bf(v.y); o.z = f2bf(v.z); o.w = f2bf(v.w);
    *(ushort4*)(ws + seg * 147456 + i) = o;
}

// ---------------- kernel 1: vocab projection tables -----------------------
__global__ __launch_bounds__(256) void k_table(
    const float* __restrict__ emb, const unsigned short* __restrict__ ws,
    const float* __restrict__ bq, const float* __restrict__ bv,
    unsigned short* __restrict__ wso)
{
    const int p  = blockIdx.y;
    const int v0 = blockIdx.x * 32;
    const int tid = threadIdx.x;
    const int lane = tid & 63, wv = tid >> 6;

    __shared__ __align__(16) unsigned short sA[32][392];

    {   // stage 32x384 emb rows, f32 -> bf16
        int r = tid >> 3;
        int srow = min(v0 + r, VOCAB_ - 1);
        const float* src = emb + (size_t)srow * NS + (tid & 7) * 48;
        unsigned short* dst = &sA[r][(tid & 7) * 48];
        #pragma unroll
        for (int j = 0; j < 6; ++j) {
            float4 a0 = *(const float4*)(src + j * 8);
            float4 a1 = *(const float4*)(src + j * 8 + 4);
            ushort4 o0, o1;
            o0.x = f2bf(a0.x); o0.y = f2bf(a0.y); o0.z = f2bf(a0.z); o0.w = f2bf(a0.w);
            o1.x = f2bf(a1.x); o1.y = f2bf(a1.y); o1.z = f2bf(a1.z); o1.w = f2bf(a1.w);
            *(ushort4*)(dst + j * 8) = o0;
            *(ushort4*)(dst + j * 8 + 4) = o1;
        }
    }
    __syncthreads();

    f32x4 acc[2][6];
    #pragma unroll
    for (int i = 0; i < 2; ++i)
        #pragma unroll
        for (int j = 0; j < 6; ++j) acc[i][j] = (f32x4){0.f, 0.f, 0.f, 0.f};

    const int colA = lane & 15;
    const int kb = (lane >> 4) * 8;
    const unsigned short* wlane =
        ws + (size_t)p * 147456 + (size_t)(wv * 96 + colA) * NS + kb;

    #pragma unroll 2
    for (int kc = 0; kc < 12; ++kc) {
        bf16x8 a[2], b[6];
        #pragma unroll
        for (int mf = 0; mf < 2; ++mf)
            a[mf] = *(const bf16x8*)&sA[mf * 16 + colA][kc * 32 + kb];
        #pragma unroll
        for (int nf = 0; nf < 6; ++nf)
            b[nf] = *(const bf16x8*)(wlane + (size_t)(nf * 16) * NS + kc * 32);
        #pragma unroll
        for (int mf = 0; mf < 2; ++mf)
            #pragma unroll
            for (int nf = 0; nf < 6; ++nf)
                acc[mf][nf] = __builtin_amdgcn_mfma_f32_16x16x32_bf16(
                    a[mf], b[nf], acc[mf][nf], 0, 0, 0);
    }

    const int r0 = (lane >> 4) * 4;
    const float scale = 0.35355339059327373f;            // 64^-0.25
    const float qscale = 0.35355339059327373f * 1.4426950408889634f; // * log2(e)

    if (p == 0) {
        unsigned short* qt_ = wso + OFF_QTAB;
        #pragma unroll
        for (int nf = 0; nf < 6; ++nf) {
            int n = wv * 96 + nf * 16 + colA;
            float bias = bq[n];
            #pragma unroll
            for (int mf = 0; mf < 2; ++mf)
                #pragma unroll
                for (int r = 0; r < 4; ++r) {
                    int row = v0 + mf * 16 + r0 + r;
                    if (row < VOCAB_)
                        qt_[(size_t)row * NS + n] = f2bf((acc[mf][nf][r] + bias) * qscale);
                }
        }
    } else if (p == 1) {
        unsigned short* kt_ = wso + OFF_KTAB;
        #pragma unroll
        for (int nf = 0; nf < 6; ++nf) {
            int n = wv * 96 + nf * 16 + colA;
            #pragma unroll
            for (int mf = 0; mf < 2; ++mf)
                #pragma unroll
                for (int r = 0; r < 4; ++r) {
                    int row = v0 + mf * 16 + r0 + r;
                    if (row < VOCAB_)
                        kt_[(size_t)row * NS + n] = f2bf(acc[mf][nf][r] * scale);
                }
        }
    } else {
        unsigned short* vt_ = wso + OFF_VTAB;
        #pragma unroll
        for (int nf = 0; nf < 6; ++nf) {
            int n = wv * 96 + nf * 16 + colA;
            float bias = bv[n];
            #pragma unroll
            for (int mf = 0; mf < 2; ++mf)
                #pragma unroll
                for (int r = 0; r < 4; ++r) {
                    int row = v0 + mf * 16 + r0 + r;
                    if (row < VOCAB_)
                        vt_[(size_t)row * NS + n] = f2bf(acc[mf][nf][r] + bias);
                }
        }
    }
}

// -------- kernel 2: fused attention (all 6 heads) + out-proj + k/v gather --
// gid < 896: attention block for (b, qtile) with bijective XCD swizzle
//   as=(gid&7)*112+(gid>>3): XCD x handles b in [16x,16x+16), qt descending.
//   Inner per-head kv-loop is verbatim round-6 attn; per-head O goes to LDS
//   sO[64][392]; after last head the k_oproj body runs on sO (Wo L2-direct)
//   and writes final f32 rows. ctx never touches global memory.
// gid >= 896: gather block (same body as round 6) with matching XCD swizzle.
__global__ __launch_bounds__(256) void k_fused(
    const int* __restrict__ x, const unsigned short* __restrict__ ws,
    const float* __restrict__ bo, float* __restrict__ out,
    float* __restrict__ out_k, float* __restrict__ out_v)
{
    const int gid = blockIdx.x;
    const int tid = threadIdx.x;

    if (gid >= NATT2) {
        // ---------------- gather path ----------------
        int g = gid - NATT2;
        int cs = (g & 7) * (NGAT / 8) + (g >> 3);
        int i = cs * 256 + tid;                 // chunk id < 2752512
        int row = i / 48;
        int c = (i - row * 48) * 8;
        int tok = x[row];
        const unsigned short* ks = ws + OFF_KTAB + (size_t)tok * NS + c;
        const unsigned short* vs = ws + OFF_VTAB + (size_t)tok * NS + c;
        ushort4 k0 = *(const ushort4*)ks;
        ushort4 k1 = *(const ushort4*)(ks + 4);
        ushort4 v0 = *(const ushort4*)vs;
        ushort4 v1 = *(const ushort4*)(vs + 4);
        const float inv = 2.8284271247461903f;  // 1/scale: ktab is pre-scaled
        float4 fk0 = {bf2f(k0.x) * inv, bf2f(k0.y) * inv, bf2f(k0.z) * inv, bf2f(k0.w) * inv};
        float4 fk1 = {bf2f(k1.x) * inv, bf2f(k1.y) * inv, bf2f(k1.z) * inv, bf2f(k1.w) * inv};
        float4 fv0 = {bf2f(v0.x), bf2f(v0.y), bf2f(v0.z), bf2f(v0.w)};
        float4 fv1 = {bf2f(v1.x), bf2f(v1.y), bf2f(v1.z), bf2f(v1.w)};
        size_t base = (size_t)row * NS + c;
        *(float4*)(out_k + base)     = fk0;
        *(float4*)(out_k + base + 4) = fk1;
        *(float4*)(out_v + base)     = fv0;
        *(float4*)(out_v + base + 4) = fv1;
        return;
    }

    // ---------------- attention + oproj path ----------------
    const int as = (gid & 7) * (NATT2 / 8) + (gid >> 3);
    const int b  = as / 7;
    const int qt = 6 - (as % 7);        // heavy (qt=6) blocks first per batch
    const int lane = tid & 63, wv = tid >> 6;

    __shared__ __align__(16) unsigned short sK[64][72];
    __shared__ __align__(16) unsigned short sVT[64][72];
    __shared__ __align__(16) unsigned short sP[4][16][72];
    __shared__ __align__(16) unsigned short sO[64][392];

    const int* xb = x + (size_t)b * T_;
    const unsigned short* qtab = ws + OFF_QTAB;
    const unsigned short* ktab = ws + OFF_KTAB;
    const unsigned short* vtab = ws + OFF_VTAB;

    const int qrow = qt * 64 + wv * 16 + (lane & 15);
    const int qtok = xb[qrow];

    f32x4 o[4];
    #pragma unroll
    for (int nf = 0; nf < 4; ++nf) o[nf] = (f32x4){0.f, 0.f, 0.f, 0.f};
    float lsum[4] = {0.f, 0.f, 0.f, 0.f};
    bf16x8 qf0, qf1;

    const int tk = tid >> 2;          // K-staging: token 0..63
    const int cc = (tid & 3) * 16;    // K-staging: d chunk
    const int vd = tid & 63;          // V-staging: d row
    const int vg = tid >> 6;          // V-staging: token group (16 tokens)

    // prefetch (h=0, kv=0)
    short8v kr0, kr1;
    unsigned short tv[16];
    {
        int tkn = xb[tk];
        const unsigned short* kset = ktab + (size_t)tkn * NS + cc;
        kr0 = *(const short8v*)kset;
        kr1 = *(const short8v*)(kset + 8);
        #pragma unroll
        for (int j = 0; j < 16; ++j) {
            int t = xb[vg * 16 + j];
            tv[j] = vtab[(size_t)t * NS + vd];
        }
    }

    int h = 0, kv = 0;
    const int NT = NH * (qt + 1);
    for (int t = 0; t < NT; ++t) {
        __syncthreads();
        // write prefetched tile into LDS
        *(short8v*)&sK[tk][cc]           = kr0;
        *(short8v*)&sK[tk][cc + 8]       = kr1;
        *(short8v*)&sVT[vd][vg * 16]     = *(const short8v*)&tv[0];
        *(short8v*)&sVT[vd][vg * 16 + 8] = *(const short8v*)&tv[8];
        __syncthreads();

        // prefetch next (h,kv) pair's K/V (latency hides under this tile)
        {
            int nh = h, nkv = kv + 1;
            if (nkv > qt) { nkv = 0; nh++; }
            if (nh < NH) {
                int base = nkv * 64;
                int tkn = xb[base + tk];
                const unsigned short* kset = ktab + (size_t)tkn * NS + nh * HD + cc;
                kr0 = *(const short8v*)kset;
                kr1 = *(const short8v*)(kset + 8);
                #pragma unroll
                for (int j = 0; j < 16; ++j) {
                    int tt = xb[base + vg * 16 + j];
                    tv[j] = vtab[(size_t)tt * NS + nh * HD + vd];
                }
            }
        }

        if (kv == 0) {  // new head: load this head's Q fragment
            const unsigned short* qbase =
                qtab + (size_t)qtok * NS + h * HD + (lane >> 4) * 8;
            qf0 = *(const bf16x8*)qbase;
            qf1 = *(const bf16x8*)(qbase + 32);
        }

        // S = Q K^T  (16 q-rows x 64 kv-cols per wave); logits already *log2e
        f32x4 s[4];
        #pragma unroll
        for (int nf = 0; nf < 4; ++nf) s[nf] = (f32x4){0.f, 0.f, 0.f, 0.f};
        #pragma unroll
        for (int nf = 0; nf < 4; ++nf) {
            bf16x8 kb0 = *(const bf16x8*)&sK[nf * 16 + (lane & 15)][(lane >> 4) * 8];
            s[nf] = __builtin_amdgcn_mfma_f32_16x16x32_bf16(qf0, kb0, s[nf], 0, 0, 0);
            bf16x8 kb1 = *(const bf16x8*)&sK[nf * 16 + (lane & 15)][32 + (lane >> 4) * 8];
            s[nf] = __builtin_amdgcn_mfma_f32_16x16x32_bf16(qf1, kb1, s[nf], 0, 0, 0);
        }

        // no-max softmax: p = exp2(s); only diagonal tile needs the mask.
        // Tile-local row of this lane's r-th acc row is wv*16 + (lane>>4)*4 + r.
        if (kv == qt) {
            const int rloc = wv * 16 + (lane >> 4) * 4;
            const int cloc = lane & 15;
            #pragma unroll
            for (int nf = 0; nf < 4; ++nf)
                #pragma unroll
                for (int r = 0; r < 4; ++r) {
                    float sv = (cloc + nf * 16 > rloc + r) ? -1e30f : s[nf][r];
                    float p = exp2f(sv);
                    s[nf][r] = p;
                    lsum[r] += p;
                }
        } else {
            #pragma unroll
            for (int nf = 0; nf < 4; ++nf)
                #pragma unroll
                for (int r = 0; r < 4; ++r) {
                    float p = exp2f(s[nf][r]);
                    s[nf][r] = p;
                    lsum[r] += p;
                }
        }

        // P (D-layout) -> per-wave LDS -> A-frag layout
        #pragma unroll
        for (int nf = 0; nf < 4; ++nf)
            #pragma unroll
            for (int r = 0; r < 4; ++r)
                sP[wv][(lane >> 4) * 4 + r][nf * 16 + (lane & 15)] = f2bf(s[nf][r]);
        asm volatile("s_waitcnt lgkmcnt(0)" ::: "memory");

        bf16x8 pa0 = *(const bf16x8*)&sP[wv][lane & 15][(lane >> 4) * 8];
        bf16x8 pa1 = *(const bf16x8*)&sP[wv][lane & 15][32 + (lane >> 4) * 8];
        #pragma unroll
        for (int nf = 0; nf < 4; ++nf) {
            bf16x8 vb0 = *(const bf16x8*)&sVT[nf * 16 + (lane & 15)][(lane >> 4) * 8];
            o[nf] = __builtin_amdgcn_mfma_f32_16x16x32_bf16(pa0, vb0, o[nf], 0, 0, 0);
            bf16x8 vb1 = *(const bf16x8*)&sVT[nf * 16 + (lane & 15)][32 + (lane >> 4) * 8];
            o[nf] = __builtin_amdgcn_mfma_f32_16x16x32_bf16(pa1, vb1, o[nf], 0, 0, 0);
        }

        if (kv == qt) {
            // head end: deferred l reduce, write O slice to sO, reset state
            float inv[4];
            #pragma unroll
            for (int r = 0; r < 4; ++r) {
                float l = lsum[r];
                #pragma unroll
                for (int off = 1; off < 16; off <<= 1)
                    l += __shfl_xor(l, off, 16);
                inv[r] = 1.0f / l;
            }
            #pragma unroll
            for (int nf = 0; nf < 4; ++nf) {
                int col = h * HD + nf * 16 + (lane & 15);
                #pragma unroll
                for (int r = 0; r < 4; ++r)
                    sO[wv * 16 + (lane >> 4) * 4 + r][col] = f2bf(o[nf][r] * inv[r]);
            }
            #pragma unroll
            for (int nf = 0; nf < 4; ++nf) o[nf] = (f32x4){0.f, 0.f, 0.f, 0.f};
            #pragma unroll
            for (int r = 0; r < 4; ++r) lsum[r] = 0.f;
            h++; kv = 0;
        } else {
            kv++;
        }
    }

    __syncthreads();   // sO complete across all waves

    // ---------------- out-projection epilogue (k_oproj body on sO) --------
    f32x4 acc[4][6];
    #pragma unroll
    for (int i = 0; i < 4; ++i)
        #pragma unroll
        for (int j = 0; j < 6; ++j) acc[i][j] = (f32x4){0.f, 0.f, 0.f, 0.f};

    const int colA = lane & 15;
    const int kb = (lane >> 4) * 8;
    const unsigned short* wlane =
        ws + OFF_WO + (size_t)(wv * 96 + colA) * NS + kb;

    #pragma unroll 2
    for (int kc = 0; kc < 12; ++kc) {
        bf16x8 a[4], bfr[6];
        #pragma unroll
        for (int mf = 0; mf < 4; ++mf)
            a[mf] = *(const bf16x8*)&sO[mf * 16 + colA][kc * 32 + kb];
        #pragma unroll
        for (int nf = 0; nf < 6; ++nf)
            bfr[nf] = *(const bf16x8*)(wlane + (size_t)(nf * 16) * NS + kc * 32);
        #pragma unroll
        for (int mf = 0; mf < 4; ++mf)
            #pragma unroll
            for (int nf = 0; nf < 6; ++nf)
                acc[mf][nf] = __builtin_amdgcn_mfma_f32_16x16x32_bf16(
                    a[mf], bfr[nf], acc[mf][nf], 0, 0, 0);
    }

    const int m0 = b * T_ + qt * 64;
    const int r0 = (lane >> 4) * 4;
    #pragma unroll
    for (int nf = 0; nf < 6; ++nf) {
        int n = wv * 96 + nf * 16 + colA;
        float bias = bo[n];
        #pragma unroll
        for (int mf = 0; mf < 4; ++mf)
            #pragma unroll
            for (int r = 0; r < 4; ++r)
                out[(size_t)(m0 + mf * 16 + r0 + r) * NS + n] = acc[mf][nf][r] + bias;
    }
}

extern "C" void kernel_launch(void* const* d_in, const int* in_sizes, int n_in,
                              void* d_out, int out_size, void* d_ws, size_t ws_size,
                              hipStream_t stream) {
    const int*   x   = (const int*)d_in[0];
    const float* emb = (const float*)d_in[1];
    const float* Wq  = (const float*)d_in[2];
    const float* bq  = (const float*)d_in[3];
    const float* Wk  = (const float*)d_in[4];
    const float* Wv  = (const float*)d_in[5];
    const float* bv  = (const float*)d_in[6];
    const float* Wo  = (const float*)d_in[7];
    const float* bo  = (const float*)d_in[8];

    float* out   = (float*)d_out;
    float* out_k = out + NOUT;
    float* out_v = out + 2 * (size_t)NOUT;
    unsigned short* ws = (unsigned short*)d_ws;

    k_prep<<<dim3(144, 4), 256, 0, stream>>>(Wq, Wk, Wv, Wo, ws);
    k_table<<<dim3(313, 3), 256, 0, stream>>>(emb, ws, bq, bv, ws);
    k_fused<<<dim3(NFUSE), 256, 0, stream>>>(x, ws, bo, out, out_k, out_v);
}

// Round 8
// 228.035 us; speedup vs baseline: 1.2880x; 1.2880x over previous
//
#include <hip/hip_runtime.h>
#include <hip/hip_bf16.h>
#include <stdint.h>

typedef __bf16 bf16x8 __attribute__((ext_vector_type(8)));
typedef short short8v __attribute__((ext_vector_type(8)));
typedef float f32x4 __attribute__((ext_vector_type(4)));

#define B_     128
#define T_     448
#define NS     384
#define NH     6
#define HD     64
#define VOCAB_ 10000
#define NOUT   22020096   // B_*T_*NS

// ws layout (ushort element offsets). Tables are bf16.
// qtab: (emb@Wq^T + bq) * scale * log2(e)  (pre-scaled for exp2 softmax)
// ktab: (emb@Wk^T) * scale        (pre-scaled; gather multiplies by 1/scale)
// vtab: (emb@Wv^T + bv)           (unscaled)
// kb/vb: DENSE gathered bf16 copies [B][T][NS] (kb pre-scaled) -> attn reads
//        sequential per-batch rows (L2-resident) instead of random table rows
// ctx : attention output, bf16 [M][384]
#define OFF_WQ   0
#define OFF_WK   147456
#define OFF_WV   294912
#define OFF_WO   442368
#define OFF_QTAB 589824
#define OFF_KTAB 4429824
#define OFF_VTAB 8269824
#define OFF_KB   12109824
#define OFF_VB   34129920
#define OFF_CTX  56150016
// end: 78170112 ushorts = 156.3 MB

#define NATT (B_ * NH * 7)        // 5376 attention blocks
#define NGAT 10752                // gather blocks (2752512 chunks / 256)

__device__ __forceinline__ unsigned short f2bf(float f) {
    union { __bf16 h; unsigned short u; } v;
    v.h = (__bf16)f;
    return v.u;
}
__device__ __forceinline__ float bf2f(unsigned short u) {
    union { uint32_t u; float f; } v; v.u = (uint32_t)u << 16;
    return v.f;
}

// ---------------- kernel 0: f32 -> bf16 weights only ----------------------
__global__ __launch_bounds__(256) void k_prep(
    const float* __restrict__ Wq, const float* __restrict__ Wk,
    const float* __restrict__ Wv, const float* __restrict__ Wo,
    unsigned short* __restrict__ ws)
{
    const float* srcs[4] = {Wq, Wk, Wv, Wo};
    const int seg = blockIdx.y;
    int i = (blockIdx.x * 256 + threadIdx.x) * 4;
    if (i >= 147456) return;
    float4 v = *(const float4*)(srcs[seg] + i);
    ushort4 o;
    o.x = f2bf(v.x); o.y = f2bf(v.y); o.z = f2bf(v.z); o.w = f2bf(v.w);
    *(ushort4*)(ws + seg * 147456 + i) = o;
}

// ---------------- kernel 1: vocab projection tables -----------------------
__global__ __launch_bounds__(256) void k_table(
    const float* __restrict__ emb, const unsigned short* __restrict__ ws,
    const float* __restrict__ bq, const float* __restrict__ bv,
    unsigned short* __restrict__ wso)
{
    const int p  = blockIdx.y;
    const int v0 = blockIdx.x * 32;
    const int tid = threadIdx.x;
    const int lane = tid & 63, wv = tid >> 6;

    __shared__ __align__(16) unsigned short sA[32][392];

    {   // stage 32x384 emb rows, f32 -> bf16
        int r = tid >> 3;
        int srow = min(v0 + r, VOCAB_ - 1);
        const float* src = emb + (size_t)srow * NS + (tid & 7) * 48;
        unsigned short* dst = &sA[r][(tid & 7) * 48];
        #pragma unroll
        for (int j = 0; j < 6; ++j) {
            float4 a0 = *(const float4*)(src + j * 8);
            float4 a1 = *(const float4*)(src + j * 8 + 4);
            ushort4 o0, o1;
            o0.x = f2bf(a0.x); o0.y = f2bf(a0.y); o0.z = f2bf(a0.z); o0.w = f2bf(a0.w);
            o1.x = f2bf(a1.x); o1.y = f2bf(a1.y); o1.z = f2bf(a1.z); o1.w = f2bf(a1.w);
            *(ushort4*)(dst + j * 8) = o0;
            *(ushort4*)(dst + j * 8 + 4) = o1;
        }
    }
    __syncthreads();

    f32x4 acc[2][6];
    #pragma unroll
    for (int i = 0; i < 2; ++i)
        #pragma unroll
        for (int j = 0; j < 6; ++j) acc[i][j] = (f32x4){0.f, 0.f, 0.f, 0.f};

    const int colA = lane & 15;
    const int kb = (lane >> 4) * 8;
    const unsigned short* wlane =
        ws + (size_t)p * 147456 + (size_t)(wv * 96 + colA) * NS + kb;

    #pragma unroll 2
    for (int kc = 0; kc < 12; ++kc) {
        bf16x8 a[2], b[6];
        #pragma unroll
        for (int mf = 0; mf < 2; ++mf)
            a[mf] = *(const bf16x8*)&sA[mf * 16 + colA][kc * 32 + kb];
        #pragma unroll
        for (int nf = 0; nf < 6; ++nf)
            b[nf] = *(const bf16x8*)(wlane + (size_t)(nf * 16) * NS + kc * 32);
        #pragma unroll
        for (int mf = 0; mf < 2; ++mf)
            #pragma unroll
            for (int nf = 0; nf < 6; ++nf)
                acc[mf][nf] = __builtin_amdgcn_mfma_f32_16x16x32_bf16(
                    a[mf], b[nf], acc[mf][nf], 0, 0, 0);
    }

    const int r0 = (lane >> 4) * 4;
    const float scale = 0.35355339059327373f;            // 64^-0.25
    const float qscale = 0.35355339059327373f * 1.4426950408889634f; // * log2(e)

    if (p == 0) {
        unsigned short* qt_ = wso + OFF_QTAB;
        #pragma unroll
        for (int nf = 0; nf < 6; ++nf) {
            int n = wv * 96 + nf * 16 + colA;
            float bias = bq[n];
            #pragma unroll
            for (int mf = 0; mf < 2; ++mf)
                #pragma unroll
                for (int r = 0; r < 4; ++r) {
                    int row = v0 + mf * 16 + r0 + r;
                    if (row < VOCAB_)
                        qt_[(size_t)row * NS + n] = f2bf((acc[mf][nf][r] + bias) * qscale);
                }
        }
    } else if (p == 1) {
        unsigned short* kt_ = wso + OFF_KTAB;
        #pragma unroll
        for (int nf = 0; nf < 6; ++nf) {
            int n = wv * 96 + nf * 16 + colA;
            #pragma unroll
            for (int mf = 0; mf < 2; ++mf)
                #pragma unroll
                for (int r = 0; r < 4; ++r) {
                    int row = v0 + mf * 16 + r0 + r;
                    if (row < VOCAB_)
                        kt_[(size_t)row * NS + n] = f2bf(acc[mf][nf][r] * scale);
                }
        }
    } else {
        unsigned short* vt_ = wso + OFF_VTAB;
        #pragma unroll
        for (int nf = 0; nf < 6; ++nf) {
            int n = wv * 96 + nf * 16 + colA;
            float bias = bv[n];
            #pragma unroll
            for (int mf = 0; mf < 2; ++mf)
                #pragma unroll
                for (int r = 0; r < 4; ++r) {
                    int row = v0 + mf * 16 + r0 + r;
                    if (row < VOCAB_)
                        vt_[(size_t)row * NS + n] = f2bf(acc[mf][nf][r] + bias);
                }
        }
    }
}

// ---------------- kernel 2: k/v gather (tables -> f32 outputs + dense bf16)
// Writes the two f32 outputs AND dense bf16 copies kb (pre-scaled) / vb for
// the attention kernel: straight byte copies of the gathered table chunks.
__global__ __launch_bounds__(256) void k_gather(
    const int* __restrict__ x, const unsigned short* __restrict__ ws,
    float* __restrict__ out_k, float* __restrict__ out_v,
    unsigned short* __restrict__ kbuf, unsigned short* __restrict__ vbuf)
{
    int i = blockIdx.x * 256 + threadIdx.x;   // ushort8-chunk id, 2752512 total
    int row = i / 48;
    int c = (i - row * 48) * 8;
    int tok = x[row];
    const unsigned short* ks = ws + OFF_KTAB + (size_t)tok * NS + c;
    const unsigned short* vs = ws + OFF_VTAB + (size_t)tok * NS + c;
    ushort4 k0 = *(const ushort4*)ks;
    ushort4 k1 = *(const ushort4*)(ks + 4);
    ushort4 v0 = *(const ushort4*)vs;
    ushort4 v1 = *(const ushort4*)(vs + 4);
    size_t bb = (size_t)row * NS + c;
    // dense bf16 copies (kb keeps the pre-scale; attn wants it scaled)
    *(ushort4*)(kbuf + bb)     = k0;
    *(ushort4*)(kbuf + bb + 4) = k1;
    *(ushort4*)(vbuf + bb)     = v0;
    *(ushort4*)(vbuf + bb + 4) = v1;
    const float inv = 2.8284271247461903f;   // 1/scale: ktab is pre-scaled
    float4 fk0 = {bf2f(k0.x) * inv, bf2f(k0.y) * inv, bf2f(k0.z) * inv, bf2f(k0.w) * inv};
    float4 fk1 = {bf2f(k1.x) * inv, bf2f(k1.y) * inv, bf2f(k1.z) * inv, bf2f(k1.w) * inv};
    float4 fv0 = {bf2f(v0.x), bf2f(v0.y), bf2f(v0.z), bf2f(v0.w)};
    float4 fv1 = {bf2f(v1.x), bf2f(v1.y), bf2f(v1.z), bf2f(v1.w)};
    *(float4*)(out_k + bb)     = fk0;
    *(float4*)(out_k + bb + 4) = fk1;
    *(float4*)(out_v + bb)     = fv0;
    *(float4*)(out_v + bb + 4) = fv1;
}

// ---------------- kernel 3: causal flash attention ------------------------
// Round-6 body, but K/V staged from the DENSE bf16 buffers (sequential
// per-batch rows, XCD-local via swizzle) instead of random table rows.
// Q still via token index from qtab. XCD swizzle: XCD x gets b in
// [16x, 16x+16) -> per-batch K/V working set (688 KB) stays L2-resident.
__global__ __launch_bounds__(256) void k_attn(
    const int* __restrict__ x, const unsigned short* __restrict__ ws,
    unsigned short* __restrict__ ctxb)
{
    const int as = (blockIdx.x & 7) * (NATT / 8) + (blockIdx.x >> 3);
    const int b  = as / 42;
    const int h  = (as / 7) % NH;
    const int qt = as % 7;
    const int tid = threadIdx.x;
    const int lane = tid & 63, wv = tid >> 6;

    __shared__ __align__(16) unsigned short sK[64][72];
    __shared__ __align__(16) unsigned short sVT[64][72];
    __shared__ __align__(16) unsigned short sP[4][16][72];

    const int* xb = x + (size_t)b * T_;
    const unsigned short* qtab = ws + OFF_QTAB;
    const unsigned short* kb_ = ws + OFF_KB + (size_t)b * T_ * NS + h * HD;
    const unsigned short* vb_ = ws + OFF_VB + (size_t)b * T_ * NS + h * HD;

    const int qrow = qt * 64 + wv * 16 + (lane & 15);
    const int qtok = xb[qrow];
    const unsigned short* qbase =
        qtab + (size_t)qtok * NS + h * HD + (lane >> 4) * 8;
    bf16x8 qf0 = *(const bf16x8*)qbase;
    bf16x8 qf1 = *(const bf16x8*)(qbase + 32);

    f32x4 o[4];
    #pragma unroll
    for (int nf = 0; nf < 4; ++nf) o[nf] = (f32x4){0.f, 0.f, 0.f, 0.f};
    float lsum[4] = {0.f, 0.f, 0.f, 0.f};

    const int tk = tid >> 2;          // K-staging: token 0..63
    const int cc = (tid & 3) * 16;    // K-staging: d chunk
    const int vd = tid & 63;          // V-staging: d row
    const int vg = tid >> 6;          // V-staging: token group (16 tokens)

    // prefetch tile 0 into registers (dense rows: stride NS)
    short8v kr0, kr1;
    unsigned short tv[16];
    {
        const unsigned short* kset = kb_ + (size_t)tk * NS + cc;
        kr0 = *(const short8v*)kset;
        kr1 = *(const short8v*)(kset + 8);
        #pragma unroll
        for (int j = 0; j < 16; ++j)
            tv[j] = vb_[(size_t)(vg * 16 + j) * NS + vd];
    }

    for (int kv = 0; kv <= qt; ++kv) {
        __syncthreads();
        // write prefetched tile into LDS
        *(short8v*)&sK[tk][cc]           = kr0;
        *(short8v*)&sK[tk][cc + 8]       = kr1;
        *(short8v*)&sVT[vd][vg * 16]     = *(const short8v*)&tv[0];
        *(short8v*)&sVT[vd][vg * 16 + 8] = *(const short8v*)&tv[8];
        __syncthreads();

        // issue NEXT tile's loads now (latency hides under this tile)
        if (kv < qt) {
            int base = (kv + 1) * 64;
            const unsigned short* kset = kb_ + (size_t)(base + tk) * NS + cc;
            kr0 = *(const short8v*)kset;
            kr1 = *(const short8v*)(kset + 8);
            #pragma unroll
            for (int j = 0; j < 16; ++j)
                tv[j] = vb_[(size_t)(base + vg * 16 + j) * NS + vd];
        }

        // S = Q K^T  (16 q-rows x 64 kv-cols per wave); logits already *log2e
        f32x4 s[4];
        #pragma unroll
        for (int nf = 0; nf < 4; ++nf) s[nf] = (f32x4){0.f, 0.f, 0.f, 0.f};
        #pragma unroll
        for (int nf = 0; nf < 4; ++nf) {
            bf16x8 kb0 = *(const bf16x8*)&sK[nf * 16 + (lane & 15)][(lane >> 4) * 8];
            s[nf] = __builtin_amdgcn_mfma_f32_16x16x32_bf16(qf0, kb0, s[nf], 0, 0, 0);
            bf16x8 kb1 = *(const bf16x8*)&sK[nf * 16 + (lane & 15)][32 + (lane >> 4) * 8];
            s[nf] = __builtin_amdgcn_mfma_f32_16x16x32_bf16(qf1, kb1, s[nf], 0, 0, 0);
        }

        // no-max softmax: p = exp2(s); only diagonal tile needs the mask.
        // Tile-local row of this lane's r-th acc row is wv*16 + (lane>>4)*4 + r.
        if (kv == qt) {
            const int rloc = wv * 16 + (lane >> 4) * 4;
            const int cloc = lane & 15;
            #pragma unroll
            for (int nf = 0; nf < 4; ++nf)
                #pragma unroll
                for (int r = 0; r < 4; ++r) {
                    float sv = (cloc + nf * 16 > rloc + r) ? -1e30f : s[nf][r];
                    float p = exp2f(sv);
                    s[nf][r] = p;
                    lsum[r] += p;
                }
        } else {
            #pragma unroll
            for (int nf = 0; nf < 4; ++nf)
                #pragma unroll
                for (int r = 0; r < 4; ++r) {
                    float p = exp2f(s[nf][r]);
                    s[nf][r] = p;
                    lsum[r] += p;
                }
        }

        // P (D-layout) -> per-wave LDS -> A-frag layout
        #pragma unroll
        for (int nf = 0; nf < 4; ++nf)
            #pragma unroll
            for (int r = 0; r < 4; ++r)
                sP[wv][(lane >> 4) * 4 + r][nf * 16 + (lane & 15)] = f2bf(s[nf][r]);
        asm volatile("s_waitcnt lgkmcnt(0)" ::: "memory");

        bf16x8 pa0 = *(const bf16x8*)&sP[wv][lane & 15][(lane >> 4) * 8];
        bf16x8 pa1 = *(const bf16x8*)&sP[wv][lane & 15][32 + (lane >> 4) * 8];
        #pragma unroll
        for (int nf = 0; nf < 4; ++nf) {
            bf16x8 vb0 = *(const bf16x8*)&sVT[nf * 16 + (lane & 15)][(lane >> 4) * 8];
            o[nf] = __builtin_amdgcn_mfma_f32_16x16x32_bf16(pa0, vb0, o[nf], 0, 0, 0);
            bf16x8 vb1 = *(const bf16x8*)&sVT[nf * 16 + (lane & 15)][32 + (lane >> 4) * 8];
            o[nf] = __builtin_amdgcn_mfma_f32_16x16x32_bf16(pa1, vb1, o[nf], 0, 0, 0);
        }
    }

    // deferred l reduce (row spread over 16 lanes of same group)
    float inv[4];
    #pragma unroll
    for (int r = 0; r < 4; ++r) {
        float l = lsum[r];
        #pragma unroll
        for (int off = 1; off < 16; off <<= 1)
            l += __shfl_xor(l, off, 16);
        inv[r] = 1.0f / l;
    }

    #pragma unroll
    for (int nf = 0; nf < 4; ++nf) {
        int col = h * HD + nf * 16 + (lane & 15);
        #pragma unroll
        for (int r = 0; r < 4; ++r) {
            int rowg = qt * 64 + wv * 16 + (lane >> 4) * 4 + r;
            ctxb[((size_t)b * T_ + rowg) * NS + col] = f2bf(o[nf][r] * inv[r]);
        }
    }
}

// ---------------- kernel 4: out-projection (ctx bf16 in ws -> d_out) ------
__global__ __launch_bounds__(256) void k_oproj(
    const unsigned short* __restrict__ ws, const float* __restrict__ bo,
    float* __restrict__ out)
{
    const int m0 = blockIdx.x * 64;
    const int tid = threadIdx.x;
    const int lane = tid & 63, wv = tid >> 6;

    __shared__ __align__(16) unsigned short sA[64][392];

    const unsigned short* ctxb = ws + OFF_CTX;

    {   // stage 64x384 ctx rows (bf16, straight copy)
        int r = tid >> 2, seg = tid & 3;
        const unsigned short* src = ctxb + (size_t)(m0 + r) * NS + seg * 96;
        unsigned short* dst = &sA[r][seg * 96];
        #pragma unroll
        for (int j = 0; j < 12; ++j)
            *(short8v*)(dst + j * 8) = *(const short8v*)(src + j * 8);
    }
    __syncthreads();

    f32x4 acc[4][6];
    #pragma unroll
    for (int i = 0; i < 4; ++i)
        #pragma unroll
        for (int j = 0; j < 6; ++j) acc[i][j] = (f32x4){0.f, 0.f, 0.f, 0.f};

    const int colA = lane & 15;
    const int kb = (lane >> 4) * 8;
    const unsigned short* wlane =
        ws + OFF_WO + (size_t)(wv * 96 + colA) * NS + kb;

    #pragma unroll 2
    for (int kc = 0; kc < 12; ++kc) {
        bf16x8 a[4], bfr[6];
        #pragma unroll
        for (int mf = 0; mf < 4; ++mf)
            a[mf] = *(const bf16x8*)&sA[mf * 16 + colA][kc * 32 + kb];
        #pragma unroll
        for (int nf = 0; nf < 6; ++nf)
            bfr[nf] = *(const bf16x8*)(wlane + (size_t)(nf * 16) * NS + kc * 32);
        #pragma unroll
        for (int mf = 0; mf < 4; ++mf)
            #pragma unroll
            for (int nf = 0; nf < 6; ++nf)
                acc[mf][nf] = __builtin_amdgcn_mfma_f32_16x16x32_bf16(
                    a[mf], bfr[nf], acc[mf][nf], 0, 0, 0);
    }

    const int r0 = (lane >> 4) * 4;
    #pragma unroll
    for (int nf = 0; nf < 6; ++nf) {
        int n = wv * 96 + nf * 16 + colA;
        float bias = bo[n];
        #pragma unroll
        for (int mf = 0; mf < 4; ++mf)
            #pragma unroll
            for (int r = 0; r < 4; ++r)
                out[(size_t)(m0 + mf * 16 + r0 + r) * NS + n] = acc[mf][nf][r] + bias;
    }
}

extern "C" void kernel_launch(void* const* d_in, const int* in_sizes, int n_in,
                              void* d_out, int out_size, void* d_ws, size_t ws_size,
                              hipStream_t stream) {
    const int*   x   = (const int*)d_in[0];
    const float* emb = (const float*)d_in[1];
    const float* Wq  = (const float*)d_in[2];
    const float* bq  = (const float*)d_in[3];
    const float* Wk  = (const float*)d_in[4];
    const float* Wv  = (const float*)d_in[5];
    const float* bv  = (const float*)d_in[6];
    const float* Wo  = (const float*)d_in[7];
    const float* bo  = (const float*)d_in[8];

    float* out   = (float*)d_out;
    float* out_k = out + NOUT;
    float* out_v = out + 2 * (size_t)NOUT;
    unsigned short* ws = (unsigned short*)d_ws;

    k_prep<<<dim3(144, 4), 256, 0, stream>>>(Wq, Wk, Wv, Wo, ws);
    k_table<<<dim3(313, 3), 256, 0, stream>>>(emb, ws, bq, bv, ws);
    k_gather<<<dim3(NGAT), 256, 0, stream>>>(x, ws, out_k, out_v,
                                             ws + OFF_KB, ws + OFF_VB);
    k_attn<<<dim3(NATT), 256, 0, stream>>>(x, ws, ws + OFF_CTX);
    k_oproj<<<dim3(896), 256, 0, stream>>>(ws, bo, out);
}

// Round 10
// 220.875 us; speedup vs baseline: 1.3297x; 1.0324x over previous
//
#include <hip/hip_runtime.h>
#include <hip/hip_bf16.h>
#include <stdint.h>

typedef __bf16 bf16x8 __attribute__((ext_vector_type(8)));
typedef short short8v __attribute__((ext_vector_type(8)));
typedef float f32x4 __attribute__((ext_vector_type(4)));

#define B_     128
#define T_     448
#define NS     384
#define NH     6
#define HD     64
#define VOCAB_ 10000
#define NOUT   22020096   // B_*T_*NS

// ws layout (ushort element offsets). Tables are bf16.
// qtab: (emb@Wq^T + bq) * scale * log2(e)  (pre-scaled for exp2 softmax)
// ktab: (emb@Wk^T) * scale        (pre-scaled; gather multiplies by 1/scale)
// vtab: (emb@Wv^T + bv)           (unscaled)
// ctx : attention output, bf16 [M][384]
#define OFF_WQ   0
#define OFF_WK   147456
#define OFF_WV   294912
#define OFF_WO   442368
#define OFF_QTAB 589824
#define OFF_KTAB 4429824
#define OFF_VTAB 8269824
#define OFF_CTX  12109824
// end: 34129920 ushorts = 68.3 MB

#define NATT3  3072               // (b, head, qtile-pair) blocks: 128*6*4
#define NGAT2  5376               // gather blocks (2752512 chunks / 512)
#define NFUSE2 (NATT3 + NGAT2)    // 8448

__device__ __forceinline__ unsigned short f2bf(float f) {
    union { __bf16 h; unsigned short u; } v;
    v.h = (__bf16)f;
    return v.u;
}
__device__ __forceinline__ float bf2f(unsigned short u) {
    union { uint32_t u; float f; } v; v.u = (uint32_t)u << 16;
    return v.f;
}

// ---------------- kernel 0: f32 -> bf16 weights only ----------------------
__global__ __launch_bounds__(256) void k_prep(
    const float* __restrict__ Wq, const float* __restrict__ Wk,
    const float* __restrict__ Wv, const float* __restrict__ Wo,
    unsigned short* __restrict__ ws)
{
    const float* srcs[4] = {Wq, Wk, Wv, Wo};
    const int seg = blockIdx.y;
    int i = (blockIdx.x * 256 + threadIdx.x) * 4;
    if (i >= 147456) return;
    float4 v = *(const float4*)(srcs[seg] + i);
    ushort4 o;
    o.x = f2bf(v.x); o.y = f2bf(v.y); o.z = f2bf(v.z); o.w = f2bf(v.w);
    *(ushort4*)(ws + seg * 147456 + i) = o;
}

// ---------------- kernel 1: vocab projection tables -----------------------
__global__ __launch_bounds__(256) void k_table(
    const float* __restrict__ emb, const unsigned short* __restrict__ ws,
    const float* __restrict__ bq, const float* __restrict__ bv,
    unsigned short* __restrict__ wso)
{
    const int p  = blockIdx.y;
    const int v0 = blockIdx.x * 32;
    const int tid = threadIdx.x;
    const int lane = tid & 63, wv = tid >> 6;

    __shared__ __align__(16) unsigned short sA[32][392];

    {   // stage 32x384 emb rows, f32 -> bf16
        int r = tid >> 3;
        int srow = min(v0 + r, VOCAB_ - 1);
        const float* src = emb + (size_t)srow * NS + (tid & 7) * 48;
        unsigned short* dst = &sA[r][(tid & 7) * 48];
        #pragma unroll
        for (int j = 0; j < 6; ++j) {
            float4 a0 = *(const float4*)(src + j * 8);
            float4 a1 = *(const float4*)(src + j * 8 + 4);
            ushort4 o0, o1;
            o0.x = f2bf(a0.x); o0.y = f2bf(a0.y); o0.z = f2bf(a0.z); o0.w = f2bf(a0.w);
            o1.x = f2bf(a1.x); o1.y = f2bf(a1.y); o1.z = f2bf(a1.z); o1.w = f2bf(a1.w);
            *(ushort4*)(dst + j * 8) = o0;
            *(ushort4*)(dst + j * 8 + 4) = o1;
        }
    }
    __syncthreads();

    f32x4 acc[2][6];
    #pragma unroll
    for (int i = 0; i < 2; ++i)
        #pragma unroll
        for (int j = 0; j < 6; ++j) acc[i][j] = (f32x4){0.f, 0.f, 0.f, 0.f};

    const int colA = lane & 15;
    const int kb = (lane >> 4) * 8;
    const unsigned short* wlane =
        ws + (size_t)p * 147456 + (size_t)(wv * 96 + colA) * NS + kb;

    #pragma unroll 2
    for (int kc = 0; kc < 12; ++kc) {
        bf16x8 a[2], b[6];
        #pragma unroll
        for (int mf = 0; mf < 2; ++mf)
            a[mf] = *(const bf16x8*)&sA[mf * 16 + colA][kc * 32 + kb];
        #pragma unroll
        for (int nf = 0; nf < 6; ++nf)
            b[nf] = *(const bf16x8*)(wlane + (size_t)(nf * 16) * NS + kc * 32);
        #pragma unroll
        for (int mf = 0; mf < 2; ++mf)
            #pragma unroll
            for (int nf = 0; nf < 6; ++nf)
                acc[mf][nf] = __builtin_amdgcn_mfma_f32_16x16x32_bf16(
                    a[mf], b[nf], acc[mf][nf], 0, 0, 0);
    }

    const int r0 = (lane >> 4) * 4;
    const float scale = 0.35355339059327373f;            // 64^-0.25
    const float qscale = 0.35355339059327373f * 1.4426950408889634f; // * log2(e)

    if (p == 0) {
        unsigned short* qt_ = wso + OFF_QTAB;
        #pragma unroll
        for (int nf = 0; nf < 6; ++nf) {
            int n = wv * 96 + nf * 16 + colA;
            float bias = bq[n];
            #pragma unroll
            for (int mf = 0; mf < 2; ++mf)
                #pragma unroll
                for (int r = 0; r < 4; ++r) {
                    int row = v0 + mf * 16 + r0 + r;
                    if (row < VOCAB_)
                        qt_[(size_t)row * NS + n] = f2bf((acc[mf][nf][r] + bias) * qscale);
                }
        }
    } else if (p == 1) {
        unsigned short* kt_ = wso + OFF_KTAB;
        #pragma unroll
        for (int nf = 0; nf < 6; ++nf) {
            int n = wv * 96 + nf * 16 + colA;
            #pragma unroll
            for (int mf = 0; mf < 2; ++mf)
                #pragma unroll
                for (int r = 0; r < 4; ++r) {
                    int row = v0 + mf * 16 + r0 + r;
                    if (row < VOCAB_)
                        kt_[(size_t)row * NS + n] = f2bf(acc[mf][nf][r] * scale);
                }
        }
    } else {
        unsigned short* vt_ = wso + OFF_VTAB;
        #pragma unroll
        for (int nf = 0; nf < 6; ++nf) {
            int n = wv * 96 + nf * 16 + colA;
            float bias = bv[n];
            #pragma unroll
            for (int mf = 0; mf < 2; ++mf)
                #pragma unroll
                for (int r = 0; r < 4; ++r) {
                    int row = v0 + mf * 16 + r0 + r;
                    if (row < VOCAB_)
                        vt_[(size_t)row * NS + n] = f2bf(acc[mf][nf][r] + bias);
                }
        }
    }
}

// ------- kernel 2: fused causal flash attention (2 q-tiles) + k/v gather --
// 512-thread blocks. gid < 3072: attention block (b, h, qtile-pair pr) via
// bijective XCD swizzle. Waves 0-3 own q-tile 2p rows, waves 4-7 own 2p+1
// (pr==3: lone q-tile 6, waves 4-7 stage+idle). K/V tile staged ONCE per kv,
// shared by both q-tiles -> table-read traffic 28->19 tiles per (b,h).
// __launch_bounds__(512,4) caps VGPR at 128 -> 4 waves/SIMD (2x round-6).
// gid >= 3072: gather block (verbatim round-6 body at 512 threads).
__global__ __launch_bounds__(512, 4) void k_fused(
    const int* __restrict__ x, const unsigned short* __restrict__ ws,
    unsigned short* __restrict__ ctxb,
    float* __restrict__ out_k, float* __restrict__ out_v)
{
    const int gid = blockIdx.x;
    const int tid = threadIdx.x;

    if (gid >= NATT3) {
        // ---------------- gather path ----------------
        int g = gid - NATT3;
        int cs = (g & 7) * (NGAT2 / 8) + (g >> 3);
        int i = cs * 512 + tid;                 // chunk id < 2752512
        int row = i / 48;
        int c = (i - row * 48) * 8;
        int tok = x[row];
        const unsigned short* ks = ws + OFF_KTAB + (size_t)tok * NS + c;
        const unsigned short* vs = ws + OFF_VTAB + (size_t)tok * NS + c;
        ushort4 k0 = *(const ushort4*)ks;
        ushort4 k1 = *(const ushort4*)(ks + 4);
        ushort4 v0 = *(const ushort4*)vs;
        ushort4 v1 = *(const ushort4*)(vs + 4);
        const float inv = 2.8284271247461903f;  // 1/scale: ktab is pre-scaled
        float4 fk0 = {bf2f(k0.x) * inv, bf2f(k0.y) * inv, bf2f(k0.z) * inv, bf2f(k0.w) * inv};
        float4 fk1 = {bf2f(k1.x) * inv, bf2f(k1.y) * inv, bf2f(k1.z) * inv, bf2f(k1.w) * inv};
        float4 fv0 = {bf2f(v0.x), bf2f(v0.y), bf2f(v0.z), bf2f(v0.w)};
        float4 fv1 = {bf2f(v1.x), bf2f(v1.y), bf2f(v1.z), bf2f(v1.w)};
        size_t base = (size_t)row * NS + c;
        *(float4*)(out_k + base)     = fk0;
        *(float4*)(out_k + base + 4) = fk1;
        *(float4*)(out_v + base)     = fv0;
        *(float4*)(out_v + base + 4) = fv1;
        return;
    }

    // ---------------- attention path ----------------
    const int as = (gid & 7) * (NATT3 / 8) + (gid >> 3);
    const int b  = as / 24;                 // 24 = NH * 4 pairs
    const int h  = (as >> 2) % NH;
    const int pr = as & 3;
    const int qta = pr * 2;                 // 0,2,4,6
    const bool lone = (pr == 3);
    const int kvmax = lone ? 6 : qta + 1;

    const int lane = tid & 63, w = tid >> 6;     // 8 waves
    const int sub = w & 3;                       // row-slot within its q-tile
    const int qt_w = lone ? 6 : (qta + (w >> 2));
    const bool active = (!lone) || (w < 4);

    __shared__ __align__(16) unsigned short sK[64][72];
    __shared__ __align__(16) unsigned short sVT[64][72];
    __shared__ __align__(16) unsigned short sP[8][16][72];

    const int* xb = x + (size_t)b * T_;
    const unsigned short* qtab = ws + OFF_QTAB;
    const unsigned short* ktab = ws + OFF_KTAB;
    const unsigned short* vtab = ws + OFF_VTAB;

    const int qrow = qt_w * 64 + sub * 16 + (lane & 15);
    const int qtok = xb[qrow];
    const unsigned short* qbase =
        qtab + (size_t)qtok * NS + h * HD + (lane >> 4) * 8;
    bf16x8 qf0 = *(const bf16x8*)qbase;
    bf16x8 qf1 = *(const bf16x8*)(qbase + 32);

    f32x4 o[4];
    #pragma unroll
    for (int nf = 0; nf < 4; ++nf) o[nf] = (f32x4){0.f, 0.f, 0.f, 0.f};
    float lsum[4] = {0.f, 0.f, 0.f, 0.f};

    const int tk = tid >> 3;          // K-staging: token 0..63 (8 thr/row)
    const int cc = (tid & 7) * 8;     // K-staging: d chunk (8 u16)
    const int vd = tid & 63;          // V-staging: d row
    const int vg = tid >> 6;          // V-staging: token group (8 tokens)

    // prefetch tile 0 into registers
    short8v kr;
    unsigned short tv[8];
    {
        int tkn = xb[tk];
        kr = *(const short8v*)(ktab + (size_t)tkn * NS + h * HD + cc);
        #pragma unroll
        for (int j = 0; j < 8; ++j) {
            int t = xb[vg * 8 + j];
            tv[j] = vtab[(size_t)t * NS + h * HD + vd];
        }
    }

    for (int kv = 0; kv <= kvmax; ++kv) {
        __syncthreads();
        // write prefetched tile into LDS
        *(short8v*)&sK[tk][cc]      = kr;
        *(short8v*)&sVT[vd][vg * 8] = *(const short8v*)&tv[0];
        __syncthreads();

        // issue NEXT tile's loads now (latency hides under this tile)
        if (kv < kvmax) {
            int base = (kv + 1) * 64;
            int tkn = xb[base + tk];
            kr = *(const short8v*)(ktab + (size_t)tkn * NS + h * HD + cc);
            #pragma unroll
            for (int j = 0; j < 8; ++j) {
                int t = xb[base + vg * 8 + j];
                tv[j] = vtab[(size_t)t * NS + h * HD + vd];
            }
        }

        const bool doQK = active && (kv <= qt_w);
        if (doQK) {
            // S = Q K^T (16 q-rows x 64 kv-cols); logits already *log2e
            f32x4 s[4];
            #pragma unroll
            for (int nf = 0; nf < 4; ++nf) s[nf] = (f32x4){0.f, 0.f, 0.f, 0.f};
            #pragma unroll
            for (int nf = 0; nf < 4; ++nf) {
                bf16x8 kb0 = *(const bf16x8*)&sK[nf * 16 + (lane & 15)][(lane >> 4) * 8];
                s[nf] = __builtin_amdgcn_mfma_f32_16x16x32_bf16(qf0, kb0, s[nf], 0, 0, 0);
                bf16x8 kb1 = *(const bf16x8*)&sK[nf * 16 + (lane & 15)][32 + (lane >> 4) * 8];
                s[nf] = __builtin_amdgcn_mfma_f32_16x16x32_bf16(qf1, kb1, s[nf], 0, 0, 0);
            }

            // no-max softmax: p = exp2(s); diag tile masks with tile-local row
            if (kv == qt_w) {
                const int rloc = sub * 16 + (lane >> 4) * 4;
                const int cloc = lane & 15;
                #pragma unroll
                for (int nf = 0; nf < 4; ++nf)
                    #pragma unroll
                    for (int r = 0; r < 4; ++r) {
                        float sv = (cloc + nf * 16 > rloc + r) ? -1e30f : s[nf][r];
                        float p = exp2f(sv);
                        s[nf][r] = p;
                        lsum[r] += p;
                    }
            } else {
                #pragma unroll
                for (int nf = 0; nf < 4; ++nf)
                    #pragma unroll
                    for (int r = 0; r < 4; ++r) {
                        float p = exp2f(s[nf][r]);
                        s[nf][r] = p;
                        lsum[r] += p;
                    }
            }

            // P (D-layout) -> per-wave LDS -> A-frag layout
            #pragma unroll
            for (int nf = 0; nf < 4; ++nf)
                #pragma unroll
                for (int r = 0; r < 4; ++r)
                    sP[w][(lane >> 4) * 4 + r][nf * 16 + (lane & 15)] = f2bf(s[nf][r]);
            asm volatile("s_waitcnt lgkmcnt(0)" ::: "memory");

            bf16x8 pa0 = *(const bf16x8*)&sP[w][lane & 15][(lane >> 4) * 8];
            bf16x8 pa1 = *(const bf16x8*)&sP[w][lane & 15][32 + (lane >> 4) * 8];
            #pragma unroll
            for (int nf = 0; nf < 4; ++nf) {
                bf16x8 vb0 = *(const bf16x8*)&sVT[nf * 16 + (lane & 15)][(lane >> 4) * 8];
                o[nf] = __builtin_amdgcn_mfma_f32_16x16x32_bf16(pa0, vb0, o[nf], 0, 0, 0);
                bf16x8 vb1 = *(const bf16x8*)&sVT[nf * 16 + (lane & 15)][32 + (lane >> 4) * 8];
                o[nf] = __builtin_amdgcn_mfma_f32_16x16x32_bf16(pa1, vb1, o[nf], 0, 0, 0);
            }
        }
    }

    if (active) {
        // deferred l reduce (row spread over 16 lanes of same group)
        float inv[4];
        #pragma unroll
        for (int r = 0; r < 4; ++r) {
            float l = lsum[r];
            #pragma unroll
            for (int off = 1; off < 16; off <<= 1)
                l += __shfl_xor(l, off, 16);
            inv[r] = 1.0f / l;
        }

        #pragma unroll
        for (int nf = 0; nf < 4; ++nf) {
            int col = h * HD + nf * 16 + (lane & 15);
            #pragma unroll
            for (int r = 0; r < 4; ++r) {
                int rowg = qt_w * 64 + sub * 16 + (lane >> 4) * 4 + r;
                ctxb[((size_t)b * T_ + rowg) * NS + col] = f2bf(o[nf][r] * inv[r]);
            }
        }
    }
}

// ---------------- kernel 3: out-projection (ctx bf16 in ws -> d_out) ------
__global__ __launch_bounds__(256) void k_oproj(
    const unsigned short* __restrict__ ws, const float* __restrict__ bo,
    float* __restrict__ out)
{
    const int m0 = blockIdx.x * 64;
    const int tid = threadIdx.x;
    const int lane = tid & 63, wv = tid >> 6;

    __shared__ __align__(16) unsigned short sA[64][392];

    const unsigned short* ctxb = ws + OFF_CTX;

    {   // stage 64x384 ctx rows (bf16, straight copy)
        int r = tid >> 2, seg = tid & 3;
        const unsigned short* src = ctxb + (size_t)(m0 + r) * NS + seg * 96;
        unsigned short* dst = &sA[r][seg * 96];
        #pragma unroll
        for (int j = 0; j < 12; ++j)
            *(short8v*)(dst + j * 8) = *(const short8v*)(src + j * 8);
    }
    __syncthreads();

    f32x4 acc[4][6];
    #pragma unroll
    for (int i = 0; i < 4; ++i)
        #pragma unroll
        for (int j = 0; j < 6; ++j) acc[i][j] = (f32x4){0.f, 0.f, 0.f, 0.f};

    const int colA = lane & 15;
    const int kb = (lane >> 4) * 8;
    const unsigned short* wlane =
        ws + OFF_WO + (size_t)(wv * 96 + colA) * NS + kb;

    #pragma unroll 2
    for (int kc = 0; kc < 12; ++kc) {
        bf16x8 a[4], bfr[6];
        #pragma unroll
        for (int mf = 0; mf < 4; ++mf)
            a[mf] = *(const bf16x8*)&sA[mf * 16 + colA][kc * 32 + kb];
        #pragma unroll
        for (int nf = 0; nf < 6; ++nf)
            bfr[nf] = *(const bf16x8*)(wlane + (size_t)(nf * 16) * NS + kc * 32);
        #pragma unroll
        for (int mf = 0; mf < 4; ++mf)
            #pragma unroll
            for (int nf = 0; nf < 6; ++nf)
                acc[mf][nf] = __builtin_amdgcn_mfma_f32_16x16x32_bf16(
                    a[mf], bfr[nf], acc[mf][nf], 0, 0, 0);
    }

    const int r0 = (lane >> 4) * 4;
    #pragma unroll
    for (int nf = 0; nf < 6; ++nf) {
        int n = wv * 96 + nf * 16 + colA;
        float bias = bo[n];
        #pragma unroll
        for (int mf = 0; mf < 4; ++mf)
            #pragma unroll
            for (int r = 0; r < 4; ++r)
                out[(size_t)(m0 + mf * 16 + r0 + r) * NS + n] = acc[mf][nf][r] + bias;
    }
}

extern "C" void kernel_launch(void* const* d_in, const int* in_sizes, int n_in,
                              void* d_out, int out_size, void* d_ws, size_t ws_size,
                              hipStream_t stream) {
    const int*   x   = (const int*)d_in[0];
    const float* emb = (const float*)d_in[1];
    const float* Wq  = (const float*)d_in[2];
    const float* bq  = (const float*)d_in[3];
    const float* Wk  = (const float*)d_in[4];
    const float* Wv  = (const float*)d_in[5];
    const float* bv  = (const float*)d_in[6];
    const float* Wo  = (const float*)d_in[7];
    const float* bo  = (const float*)d_in[8];

    float* out   = (float*)d_out;
    float* out_k = out + NOUT;
    float* out_v = out + 2 * (size_t)NOUT;
    unsigned short* ws = (unsigned short*)d_ws;

    k_prep<<<dim3(144, 4), 256, 0, stream>>>(Wq, Wk, Wv, Wo, ws);
    k_table<<<dim3(313, 3), 256, 0, stream>>>(emb, ws, bq, bv, ws);
    k_fused<<<dim3(NFUSE2), 512, 0, stream>>>(x, ws, ws + OFF_CTX,
                                              out_k, out_v);
    k_oproj<<<dim3(896), 256, 0, stream>>>(ws, bo, out);
}

// Round 13
// 197.183 us; speedup vs baseline: 1.4895x; 1.1202x over previous
//
#include <hip/hip_runtime.h>
#include <hip/hip_bf16.h>
#include <stdint.h>

typedef __bf16 bf16x8 __attribute__((ext_vector_type(8)));
typedef short short8v __attribute__((ext_vector_type(8)));
typedef float f32x4 __attribute__((ext_vector_type(4)));

#define B_     128
#define T_     448
#define NS     384
#define NH     6
#define HD     64
#define VOCAB_ 10000
#define NOUT   22020096   // B_*T_*NS

// ws layout (ushort element offsets). Tables are bf16.
// qtab: (emb@Wq^T + bq) * scale * log2(e)  (pre-scaled for exp2 softmax)
// ktab: (emb@Wk^T) * scale        (pre-scaled; gather multiplies by 1/scale)
// vtab: (emb@Wv^T + bv)           (unscaled)
// ctx : attention output, bf16 [M][384]
#define OFF_WQ   0
#define OFF_WK   147456
#define OFF_WV   294912
#define OFF_WO   442368
#define OFF_QTAB 589824
#define OFF_KTAB 4429824
#define OFF_VTAB 8269824
#define OFF_CTX  12109824
// end: 34129920 ushorts = 68.3 MB

#define NATT (B_ * NH * 7)        // 5376 attention blocks
#define NGAT 10752                // gather blocks (2752512 chunks / 256)
#define NFUSE (NATT * 3)          // 16128 fused-grid blocks (div by 8)

__device__ __forceinline__ unsigned short f2bf(float f) {
    // native f32->bf16 convert (RTNE on gfx950)
    union { __bf16 h; unsigned short u; } v;
    v.h = (__bf16)f;
    return v.u;
}
__device__ __forceinline__ float bf2f(unsigned short u) {
    union { uint32_t u; float f; } v; v.u = (uint32_t)u << 16;
    return v.f;
}

// ---------------- kernel 0: f32 -> bf16 weights only ----------------------
__global__ __launch_bounds__(256) void k_prep(
    const float* __restrict__ Wq, const float* __restrict__ Wk,
    const float* __restrict__ Wv, const float* __restrict__ Wo,
    unsigned short* __restrict__ ws)
{
    const float* srcs[4] = {Wq, Wk, Wv, Wo};
    const int seg = blockIdx.y;
    int i = (blockIdx.x * 256 + threadIdx.x) * 4;
    if (i >= 147456) return;
    float4 v = *(const float4*)(srcs[seg] + i);
    ushort4 o;
    o.x = f2bf(v.x); o.y = f2bf(v.y); o.z = f2bf(v.z); o.w = f2bf(v.w);
    *(ushort4*)(ws + seg * 147456 + i) = o;
}

// ---------------- kernel 1: vocab projection tables -----------------------
// grid (313, 3): 32 vocab rows per block; y: 0=q,1=k,2=v.
__global__ __launch_bounds__(256) void k_table(
    const float* __restrict__ emb, const unsigned short* __restrict__ ws,
    const float* __restrict__ bq, const float* __restrict__ bv,
    unsigned short* __restrict__ wso)
{
    const int p  = blockIdx.y;
    const int v0 = blockIdx.x * 32;
    const int tid = threadIdx.x;
    const int lane = tid & 63, wv = tid >> 6;

    __shared__ __align__(16) unsigned short sA[32][392];

    {   // stage 32x384 emb rows, f32 -> bf16
        int r = tid >> 3;
        int srow = min(v0 + r, VOCAB_ - 1);
        const float* src = emb + (size_t)srow * NS + (tid & 7) * 48;
        unsigned short* dst = &sA[r][(tid & 7) * 48];
        #pragma unroll
        for (int j = 0; j < 6; ++j) {
            float4 a0 = *(const float4*)(src + j * 8);
            float4 a1 = *(const float4*)(src + j * 8 + 4);
            ushort4 o0, o1;
            o0.x = f2bf(a0.x); o0.y = f2bf(a0.y); o0.z = f2bf(a0.z); o0.w = f2bf(a0.w);
            o1.x = f2bf(a1.x); o1.y = f2bf(a1.y); o1.z = f2bf(a1.z); o1.w = f2bf(a1.w);
            *(ushort4*)(dst + j * 8) = o0;
            *(ushort4*)(dst + j * 8 + 4) = o1;
        }
    }
    __syncthreads();

    f32x4 acc[2][6];
    #pragma unroll
    for (int i = 0; i < 2; ++i)
        #pragma unroll
        for (int j = 0; j < 6; ++j) acc[i][j] = (f32x4){0.f, 0.f, 0.f, 0.f};

    const int colA = lane & 15;
    const int kb = (lane >> 4) * 8;
    const unsigned short* wlane =
        ws + (size_t)p * 147456 + (size_t)(wv * 96 + colA) * NS + kb;

    #pragma unroll 2
    for (int kc = 0; kc < 12; ++kc) {
        bf16x8 a[2], b[6];
        #pragma unroll
        for (int mf = 0; mf < 2; ++mf)
            a[mf] = *(const bf16x8*)&sA[mf * 16 + colA][kc * 32 + kb];
        #pragma unroll
        for (int nf = 0; nf < 6; ++nf)
            b[nf] = *(const bf16x8*)(wlane + (size_t)(nf * 16) * NS + kc * 32);
        #pragma unroll
        for (int mf = 0; mf < 2; ++mf)
            #pragma unroll
            for (int nf = 0; nf < 6; ++nf)
                acc[mf][nf] = __builtin_amdgcn_mfma_f32_16x16x32_bf16(
                    a[mf], b[nf], acc[mf][nf], 0, 0, 0);
    }

    const int r0 = (lane >> 4) * 4;
    const float scale = 0.35355339059327373f;            // 64^-0.25
    const float qscale = 0.35355339059327373f * 1.4426950408889634f; // * log2(e)

    if (p == 0) {
        unsigned short* qt_ = wso + OFF_QTAB;
        #pragma unroll
        for (int nf = 0; nf < 6; ++nf) {
            int n = wv * 96 + nf * 16 + colA;
            float bias = bq[n];
            #pragma unroll
            for (int mf = 0; mf < 2; ++mf)
                #pragma unroll
                for (int r = 0; r < 4; ++r) {
                    int row = v0 + mf * 16 + r0 + r;
                    if (row < VOCAB_)
                        qt_[(size_t)row * NS + n] = f2bf((acc[mf][nf][r] + bias) * qscale);
                }
        }
    } else if (p == 1) {
        unsigned short* kt_ = wso + OFF_KTAB;
        #pragma unroll
        for (int nf = 0; nf < 6; ++nf) {
            int n = wv * 96 + nf * 16 + colA;
            #pragma unroll
            for (int mf = 0; mf < 2; ++mf)
                #pragma unroll
                for (int r = 0; r < 4; ++r) {
                    int row = v0 + mf * 16 + r0 + r;
                    if (row < VOCAB_)
                        kt_[(size_t)row * NS + n] = f2bf(acc[mf][nf][r] * scale);
                }
        }
    } else {
        unsigned short* vt_ = wso + OFF_VTAB;
        #pragma unroll
        for (int nf = 0; nf < 6; ++nf) {
            int n = wv * 96 + nf * 16 + colA;
            float bias = bv[n];
            #pragma unroll
            for (int mf = 0; mf < 2; ++mf)
                #pragma unroll
                for (int r = 0; r < 4; ++r) {
                    int row = v0 + mf * 16 + r0 + r;
                    if (row < VOCAB_)
                        vt_[(size_t)row * NS + n] = f2bf(acc[mf][nf][r] + bias);
                }
        }
    }
}

// ---------------- kernel 2: fused causal flash attention + k/v gather -----
// Round-6 structure (best measured: 192.9 us) + ONE change: double-buffered
// K/V LDS -> single barrier per kv-tile. Safety: a wave re-writes buffer p
// at iter kv+2 only after barrier kv+1, which all waves reach only after
// their iter-kv reads of buffer p (read p -> write p^1 -> barrier).
// __launch_bounds__(256,4) nudges VGPR 132 -> <=128 (occupancy doubles if
// honored; 4-reg overage usually rematerializes, not spills).
__global__ __launch_bounds__(256, 4) void k_attn_gather(
    const int* __restrict__ x, const unsigned short* __restrict__ ws,
    unsigned short* __restrict__ ctxb,
    float* __restrict__ out_k, float* __restrict__ out_v)
{
    const int swz = (blockIdx.x & 7) * (NFUSE / 8) + (blockIdx.x >> 3);
    const int r3 = swz % 3;
    const int q3 = swz / 3;

    if (r3 != 0) {
        // ---------------- gather path (2 of every 3 blocks) ----------------
        int i = (2 * q3 + (r3 - 1)) * 256 + threadIdx.x;  // chunk id < 2752512
        int row = i / 48;
        int c = (i - row * 48) * 8;
        int tok = x[row];
        const unsigned short* ks = ws + OFF_KTAB + (size_t)tok * NS + c;
        const unsigned short* vs = ws + OFF_VTAB + (size_t)tok * NS + c;
        ushort4 k0 = *(const ushort4*)ks;
        ushort4 k1 = *(const ushort4*)(ks + 4);
        ushort4 v0 = *(const ushort4*)vs;
        ushort4 v1 = *(const ushort4*)(vs + 4);
        const float inv = 2.8284271247461903f;   // 1/scale: ktab is pre-scaled
        float4 fk0 = {bf2f(k0.x) * inv, bf2f(k0.y) * inv, bf2f(k0.z) * inv, bf2f(k0.w) * inv};
        float4 fk1 = {bf2f(k1.x) * inv, bf2f(k1.y) * inv, bf2f(k1.z) * inv, bf2f(k1.w) * inv};
        float4 fv0 = {bf2f(v0.x), bf2f(v0.y), bf2f(v0.z), bf2f(v0.w)};
        float4 fv1 = {bf2f(v1.x), bf2f(v1.y), bf2f(v1.z), bf2f(v1.w)};
        size_t base = (size_t)row * NS + c;
        *(float4*)(out_k + base)     = fk0;
        *(float4*)(out_k + base + 4) = fk1;
        *(float4*)(out_v + base)     = fv0;
        *(float4*)(out_v + base + 4) = fv1;
        return;
    }

    // ---------------- attention path ----------------
    const int bid = q3;
    const int qt = bid % 7;
    const int h  = (bid / 7) % NH;
    const int b  = bid / (7 * NH);
    const int tid = threadIdx.x;
    const int lane = tid & 63, wv = tid >> 6;

    __shared__ __align__(16) unsigned short sK[2][64][72];
    __shared__ __align__(16) unsigned short sVT[2][64][72];
    __shared__ __align__(16) unsigned short sP[4][16][72];

    const int* xb = x + (size_t)b * T_;
    const unsigned short* qtab = ws + OFF_QTAB;
    const unsigned short* ktab = ws + OFF_KTAB;
    const unsigned short* vtab = ws + OFF_VTAB;

    const int qrow = qt * 64 + wv * 16 + (lane & 15);
    const int qtok = xb[qrow];
    const unsigned short* qbase =
        qtab + (size_t)qtok * NS + h * HD + (lane >> 4) * 8;
    bf16x8 qf0 = *(const bf16x8*)qbase;
    bf16x8 qf1 = *(const bf16x8*)(qbase + 32);

    f32x4 o[4];
    #pragma unroll
    for (int nf = 0; nf < 4; ++nf) o[nf] = (f32x4){0.f, 0.f, 0.f, 0.f};
    float lsum[4] = {0.f, 0.f, 0.f, 0.f};

    const int tk = tid >> 2;          // K-staging: token 0..63
    const int cc = (tid & 3) * 16;    // K-staging: d chunk
    const int vd = tid & 63;          // V-staging: d row
    const int vg = tid >> 6;          // V-staging: token group (16 tokens)

    // prefetch tile 0 into registers
    short8v kr0, kr1;
    unsigned short tv[16];
    {
        int tkn = xb[tk];
        const unsigned short* kset = ktab + (size_t)tkn * NS + h * HD + cc;
        kr0 = *(const short8v*)kset;
        kr1 = *(const short8v*)(kset + 8);
        #pragma unroll
        for (int j = 0; j < 16; ++j) {
            int t = xb[vg * 16 + j];
            tv[j] = vtab[(size_t)t * NS + h * HD + vd];
        }
    }

    for (int kv = 0; kv <= qt; ++kv) {
        const int pb = kv & 1;
        // write prefetched tile into LDS buffer pb; the other buffer may
        // still be read by slower waves (they're pre-barrier in iter kv-1).
        *(short8v*)&sK[pb][tk][cc]           = kr0;
        *(short8v*)&sK[pb][tk][cc + 8]       = kr1;
        *(short8v*)&sVT[pb][vd][vg * 16]     = *(const short8v*)&tv[0];
        *(short8v*)&sVT[pb][vd][vg * 16 + 8] = *(const short8v*)&tv[8];
        __syncthreads();   // single barrier per tile: buffer pb now complete

        // issue NEXT tile's loads now; latency hides under this tile's
        // MFMA + exp work (results needed only at next iteration's writes).
        if (kv < qt) {
            int base = (kv + 1) * 64;
            int tkn = xb[base + tk];
            const unsigned short* kset = ktab + (size_t)tkn * NS + h * HD + cc;
            kr0 = *(const short8v*)kset;
            kr1 = *(const short8v*)(kset + 8);
            #pragma unroll
            for (int j = 0; j < 16; ++j) {
                int t = xb[base + vg * 16 + j];
                tv[j] = vtab[(size_t)t * NS + h * HD + vd];
            }
        }

        // S = Q K^T  (16 q-rows x 64 kv-cols per wave); logits already *log2e
        f32x4 s[4];
        #pragma unroll
        for (int nf = 0; nf < 4; ++nf) s[nf] = (f32x4){0.f, 0.f, 0.f, 0.f};
        #pragma unroll
        for (int nf = 0; nf < 4; ++nf) {
            bf16x8 kb0 = *(const bf16x8*)&sK[pb][nf * 16 + (lane & 15)][(lane >> 4) * 8];
            s[nf] = __builtin_amdgcn_mfma_f32_16x16x32_bf16(qf0, kb0, s[nf], 0, 0, 0);
            bf16x8 kb1 = *(const bf16x8*)&sK[pb][nf * 16 + (lane & 15)][32 + (lane >> 4) * 8];
            s[nf] = __builtin_amdgcn_mfma_f32_16x16x32_bf16(qf1, kb1, s[nf], 0, 0, 0);
        }

        // no-max softmax: p = exp2(s); only diagonal tile needs the mask.
        // Tile-local row of this lane's r-th acc row is wv*16 + (lane>>4)*4 + r.
        if (kv == qt) {
            const int rloc = wv * 16 + (lane >> 4) * 4;   // tile-local row base
            const int cloc = lane & 15;
            #pragma unroll
            for (int nf = 0; nf < 4; ++nf)
                #pragma unroll
                for (int r = 0; r < 4; ++r) {
                    float sv = (cloc + nf * 16 > rloc + r) ? -1e30f : s[nf][r];
                    float p = exp2f(sv);
                    s[nf][r] = p;
                    lsum[r] += p;
                }
        } else {
            #pragma unroll
            for (int nf = 0; nf < 4; ++nf)
                #pragma unroll
                for (int r = 0; r < 4; ++r) {
                    float p = exp2f(s[nf][r]);
                    s[nf][r] = p;
                    lsum[r] += p;
                }
        }

        // P (D-layout) -> per-wave LDS -> A-frag layout
        #pragma unroll
        for (int nf = 0; nf < 4; ++nf)
            #pragma unroll
            for (int r = 0; r < 4; ++r)
                sP[wv][(lane >> 4) * 4 + r][nf * 16 + (lane & 15)] = f2bf(s[nf][r]);
        asm volatile("s_waitcnt lgkmcnt(0)" ::: "memory");

        bf16x8 pa0 = *(const bf16x8*)&sP[wv][lane & 15][(lane >> 4) * 8];
        bf16x8 pa1 = *(const bf16x8*)&sP[wv][lane & 15][32 + (lane >> 4) * 8];
        #pragma unroll
        for (int nf = 0; nf < 4; ++nf) {
            bf16x8 vb0 = *(const bf16x8*)&sVT[pb][nf * 16 + (lane & 15)][(lane >> 4) * 8];
            o[nf] = __builtin_amdgcn_mfma_f32_16x16x32_bf16(pa0, vb0, o[nf], 0, 0, 0);
            bf16x8 vb1 = *(const bf16x8*)&sVT[pb][nf * 16 + (lane & 15)][32 + (lane >> 4) * 8];
            o[nf] = __builtin_amdgcn_mfma_f32_16x16x32_bf16(pa1, vb1, o[nf], 0, 0, 0);
        }
    }

    // deferred l reduce (row spread over 16 lanes of same group)
    float inv[4];
    #pragma unroll
    for (int r = 0; r < 4; ++r) {
        float l = lsum[r];
        #pragma unroll
        for (int off = 1; off < 16; off <<= 1)
            l += __shfl_xor(l, off, 16);
        inv[r] = 1.0f / l;
    }

    #pragma unroll
    for (int nf = 0; nf < 4; ++nf) {
        int col = h * HD + nf * 16 + (lane & 15);
        #pragma unroll
        for (int r = 0; r < 4; ++r) {
            int rowg = qt * 64 + wv * 16 + (lane >> 4) * 4 + r;
            ctxb[((size_t)b * T_ + rowg) * NS + col] = f2bf(o[nf][r] * inv[r]);
        }
    }
}

// ---------------- kernel 3: out-projection (ctx bf16 in ws -> d_out) ------
// A-tile staged once; B register-direct from L2-hot Wo; no barriers in K-loop.
__global__ __launch_bounds__(256) void k_oproj(
    const unsigned short* __restrict__ ws, const float* __restrict__ bo,
    float* __restrict__ out)
{
    const int m0 = blockIdx.x * 64;
    const int tid = threadIdx.x;
    const int lane = tid & 63, wv = tid >> 6;

    __shared__ __align__(16) unsigned short sA[64][392];

    const unsigned short* ctxb = ws + OFF_CTX;

    {   // stage 64x384 ctx rows (bf16, straight copy)
        int r = tid >> 2, seg = tid & 3;
        const unsigned short* src = ctxb + (size_t)(m0 + r) * NS + seg * 96;
        unsigned short* dst = &sA[r][seg * 96];
        #pragma unroll
        for (int j = 0; j < 12; ++j)
            *(short8v*)(dst + j * 8) = *(const short8v*)(src + j * 8);
    }
    __syncthreads();

    f32x4 acc[4][6];
    #pragma unroll
    for (int i = 0; i < 4; ++i)
        #pragma unroll
        for (int j = 0; j < 6; ++j) acc[i][j] = (f32x4){0.f, 0.f, 0.f, 0.f};

    const int colA = lane & 15;
    const int kb = (lane >> 4) * 8;
    const unsigned short* wlane =
        ws + OFF_WO + (size_t)(wv * 96 + colA) * NS + kb;

    #pragma unroll 2
    for (int kc = 0; kc < 12; ++kc) {
        bf16x8 a[4], bfr[6];
        #pragma unroll
        for (int mf = 0; mf < 4; ++mf)
            a[mf] = *(const bf16x8*)&sA[mf * 16 + colA][kc * 32 + kb];
        #pragma unroll
        for (int nf = 0; nf < 6; ++nf)
            bfr[nf] = *(const bf16x8*)(wlane + (size_t)(nf * 16) * NS + kc * 32);
        #pragma unroll
        for (int mf = 0; mf < 4; ++mf)
            #pragma unroll
            for (int nf = 0; nf < 6; ++nf)
                acc[mf][nf] = __builtin_amdgcn_mfma_f32_16x16x32_bf16(
                    a[mf], bfr[nf], acc[mf][nf], 0, 0, 0);
    }

    const int r0 = (lane >> 4) * 4;
    #pragma unroll
    for (int nf = 0; nf < 6; ++nf) {
        int n = wv * 96 + nf * 16 + colA;
        float bias = bo[n];
        #pragma unroll
        for (int mf = 0; mf < 4; ++mf)
            #pragma unroll
            for (int r = 0; r < 4; ++r)
                out[(size_t)(m0 + mf * 16 + r0 + r) * NS + n] = acc[mf][nf][r] + bias;
    }
}

extern "C" void kernel_launch(void* const* d_in, const int* in_sizes, int n_in,
                              void* d_out, int out_size, void* d_ws, size_t ws_size,
                              hipStream_t stream) {
    const int*   x   = (const int*)d_in[0];
    const float* emb = (const float*)d_in[1];
    const float* Wq  = (const float*)d_in[2];
    const float* bq  = (const float*)d_in[3];
    const float* Wk  = (const float*)d_in[4];
    const float* Wv  = (const float*)d_in[5];
    const float* bv  = (const float*)d_in[6];
    const float* Wo  = (const float*)d_in[7];
    const float* bo  = (const float*)d_in[8];

    float* out   = (float*)d_out;
    float* out_k = out + NOUT;
    float* out_v = out + 2 * (size_t)NOUT;
    unsigned short* ws = (unsigned short*)d_ws;

    k_prep<<<dim3(144, 4), 256, 0, stream>>>(Wq, Wk, Wv, Wo, ws);
    k_table<<<dim3(313, 3), 256, 0, stream>>>(emb, ws, bq, bv, ws);
    k_attn_gather<<<dim3(NFUSE), 256, 0, stream>>>(x, ws, ws + OFF_CTX,
                                                   out_k, out_v);
    k_oproj<<<dim3(896), 256, 0, stream>>>(ws, bo, out);
}

// Round 14
// 193.095 us; speedup vs baseline: 1.5210x; 1.0212x over previous
//
#include <hip/hip_runtime.h>
#include <hip/hip_bf16.h>
#include <stdint.h>

typedef __bf16 bf16x8 __attribute__((ext_vector_type(8)));
typedef short short8v __attribute__((ext_vector_type(8)));
typedef float f32x4 __attribute__((ext_vector_type(4)));

#define B_     128
#define T_     448
#define NS     384
#define NH     6
#define HD     64
#define VOCAB_ 10000
#define NOUT   22020096   // B_*T_*NS

// ws layout (ushort element offsets). Tables are bf16.
// qtab: (emb@Wq^T + bq) * scale * log2(e)  (pre-scaled for exp2 softmax)
// ktab: (emb@Wk^T) * scale        (pre-scaled; gather multiplies by 1/scale)
// vtab: (emb@Wv^T + bv)           (unscaled)
// ctx : attention output, bf16 [M][384]
#define OFF_WQ   0
#define OFF_WK   147456
#define OFF_WV   294912
#define OFF_WO   442368
#define OFF_QTAB 589824
#define OFF_KTAB 4429824
#define OFF_VTAB 8269824
#define OFF_CTX  12109824
// end: 34129920 ushorts = 68.3 MB

#define NATT (B_ * NH * 7)        // 5376 attention blocks
#define NGAT 10752                // gather blocks (2752512 chunks / 256)
#define NFUSE (NATT * 3)          // 16128 fused-grid blocks (div by 8)

__device__ __forceinline__ unsigned short f2bf(float f) {
    // native f32->bf16 convert (RTNE on gfx950)
    union { __bf16 h; unsigned short u; } v;
    v.h = (__bf16)f;
    return v.u;
}
__device__ __forceinline__ float bf2f(unsigned short u) {
    union { uint32_t u; float f; } v; v.u = (uint32_t)u << 16;
    return v.f;
}

// ---------------- kernel 0: f32 -> bf16 weights only ----------------------
__global__ __launch_bounds__(256) void k_prep(
    const float* __restrict__ Wq, const float* __restrict__ Wk,
    const float* __restrict__ Wv, const float* __restrict__ Wo,
    unsigned short* __restrict__ ws)
{
    const float* srcs[4] = {Wq, Wk, Wv, Wo};
    const int seg = blockIdx.y;
    int i = (blockIdx.x * 256 + threadIdx.x) * 4;
    if (i >= 147456) return;
    float4 v = *(const float4*)(srcs[seg] + i);
    ushort4 o;
    o.x = f2bf(v.x); o.y = f2bf(v.y); o.z = f2bf(v.z); o.w = f2bf(v.w);
    *(ushort4*)(ws + seg * 147456 + i) = o;
}

// ---------------- kernel 1: vocab projection tables -----------------------
// grid (313, 3): 32 vocab rows per block; y: 0=q,1=k,2=v.
__global__ __launch_bounds__(256) void k_table(
    const float* __restrict__ emb, const unsigned short* __restrict__ ws,
    const float* __restrict__ bq, const float* __restrict__ bv,
    unsigned short* __restrict__ wso)
{
    const int p  = blockIdx.y;
    const int v0 = blockIdx.x * 32;
    const int tid = threadIdx.x;
    const int lane = tid & 63, wv = tid >> 6;

    __shared__ __align__(16) unsigned short sA[32][392];

    {   // stage 32x384 emb rows, f32 -> bf16
        int r = tid >> 3;
        int srow = min(v0 + r, VOCAB_ - 1);
        const float* src = emb + (size_t)srow * NS + (tid & 7) * 48;
        unsigned short* dst = &sA[r][(tid & 7) * 48];
        #pragma unroll
        for (int j = 0; j < 6; ++j) {
            float4 a0 = *(const float4*)(src + j * 8);
            float4 a1 = *(const float4*)(src + j * 8 + 4);
            ushort4 o0, o1;
            o0.x = f2bf(a0.x); o0.y = f2bf(a0.y); o0.z = f2bf(a0.z); o0.w = f2bf(a0.w);
            o1.x = f2bf(a1.x); o1.y = f2bf(a1.y); o1.z = f2bf(a1.z); o1.w = f2bf(a1.w);
            *(ushort4*)(dst + j * 8) = o0;
            *(ushort4*)(dst + j * 8 + 4) = o1;
        }
    }
    __syncthreads();

    f32x4 acc[2][6];
    #pragma unroll
    for (int i = 0; i < 2; ++i)
        #pragma unroll
        for (int j = 0; j < 6; ++j) acc[i][j] = (f32x4){0.f, 0.f, 0.f, 0.f};

    const int colA = lane & 15;
    const int kb = (lane >> 4) * 8;
    const unsigned short* wlane =
        ws + (size_t)p * 147456 + (size_t)(wv * 96 + colA) * NS + kb;

    #pragma unroll 2
    for (int kc = 0; kc < 12; ++kc) {
        bf16x8 a[2], b[6];
        #pragma unroll
        for (int mf = 0; mf < 2; ++mf)
            a[mf] = *(const bf16x8*)&sA[mf * 16 + colA][kc * 32 + kb];
        #pragma unroll
        for (int nf = 0; nf < 6; ++nf)
            b[nf] = *(const bf16x8*)(wlane + (size_t)(nf * 16) * NS + kc * 32);
        #pragma unroll
        for (int mf = 0; mf < 2; ++mf)
            #pragma unroll
            for (int nf = 0; nf < 6; ++nf)
                acc[mf][nf] = __builtin_amdgcn_mfma_f32_16x16x32_bf16(
                    a[mf], b[nf], acc[mf][nf], 0, 0, 0);
    }

    const int r0 = (lane >> 4) * 4;
    const float scale = 0.35355339059327373f;            // 64^-0.25
    const float qscale = 0.35355339059327373f * 1.4426950408889634f; // * log2(e)

    if (p == 0) {
        unsigned short* qt_ = wso + OFF_QTAB;
        #pragma unroll
        for (int nf = 0; nf < 6; ++nf) {
            int n = wv * 96 + nf * 16 + colA;
            float bias = bq[n];
            #pragma unroll
            for (int mf = 0; mf < 2; ++mf)
                #pragma unroll
                for (int r = 0; r < 4; ++r) {
                    int row = v0 + mf * 16 + r0 + r;
                    if (row < VOCAB_)
                        qt_[(size_t)row * NS + n] = f2bf((acc[mf][nf][r] + bias) * qscale);
                }
        }
    } else if (p == 1) {
        unsigned short* kt_ = wso + OFF_KTAB;
        #pragma unroll
        for (int nf = 0; nf < 6; ++nf) {
            int n = wv * 96 + nf * 16 + colA;
            #pragma unroll
            for (int mf = 0; mf < 2; ++mf)
                #pragma unroll
                for (int r = 0; r < 4; ++r) {
                    int row = v0 + mf * 16 + r0 + r;
                    if (row < VOCAB_)
                        kt_[(size_t)row * NS + n] = f2bf(acc[mf][nf][r] * scale);
                }
        }
    } else {
        unsigned short* vt_ = wso + OFF_VTAB;
        #pragma unroll
        for (int nf = 0; nf < 6; ++nf) {
            int n = wv * 96 + nf * 16 + colA;
            float bias = bv[n];
            #pragma unroll
            for (int mf = 0; mf < 2; ++mf)
                #pragma unroll
                for (int r = 0; r < 4; ++r) {
                    int row = v0 + mf * 16 + r0 + r;
                    if (row < VOCAB_)
                        vt_[(size_t)row * NS + n] = f2bf(acc[mf][nf][r] + bias);
                }
        }
    }
}

// ---------------- kernel 2: fused causal flash attention + k/v gather -----
// Round-6 structure (best measured: 192.9 us). Single change vs round 6:
// __launch_bounds__(256,4) to cap VGPR at <=128 (occupancy 3->4 waves/SIMD
// if honored spill-free; LDS 27.6KB permits 5 blocks/CU so LDS is not the
// binding limit, unlike the round-13 dbuf variant whose 46KB was).
__global__ __launch_bounds__(256, 4) void k_attn_gather(
    const int* __restrict__ x, const unsigned short* __restrict__ ws,
    unsigned short* __restrict__ ctxb,
    float* __restrict__ out_k, float* __restrict__ out_v)
{
    const int swz = (blockIdx.x & 7) * (NFUSE / 8) + (blockIdx.x >> 3);
    const int r3 = swz % 3;
    const int q3 = swz / 3;

    if (r3 != 0) {
        // ---------------- gather path (2 of every 3 blocks) ----------------
        int i = (2 * q3 + (r3 - 1)) * 256 + threadIdx.x;  // chunk id < 2752512
        int row = i / 48;
        int c = (i - row * 48) * 8;
        int tok = x[row];
        const unsigned short* ks = ws + OFF_KTAB + (size_t)tok * NS + c;
        const unsigned short* vs = ws + OFF_VTAB + (size_t)tok * NS + c;
        ushort4 k0 = *(const ushort4*)ks;
        ushort4 k1 = *(const ushort4*)(ks + 4);
        ushort4 v0 = *(const ushort4*)vs;
        ushort4 v1 = *(const ushort4*)(vs + 4);
        const float inv = 2.8284271247461903f;   // 1/scale: ktab is pre-scaled
        float4 fk0 = {bf2f(k0.x) * inv, bf2f(k0.y) * inv, bf2f(k0.z) * inv, bf2f(k0.w) * inv};
        float4 fk1 = {bf2f(k1.x) * inv, bf2f(k1.y) * inv, bf2f(k1.z) * inv, bf2f(k1.w) * inv};
        float4 fv0 = {bf2f(v0.x), bf2f(v0.y), bf2f(v0.z), bf2f(v0.w)};
        float4 fv1 = {bf2f(v1.x), bf2f(v1.y), bf2f(v1.z), bf2f(v1.w)};
        size_t base = (size_t)row * NS + c;
        *(float4*)(out_k + base)     = fk0;
        *(float4*)(out_k + base + 4) = fk1;
        *(float4*)(out_v + base)     = fv0;
        *(float4*)(out_v + base + 4) = fv1;
        return;
    }

    // ---------------- attention path ----------------
    const int bid = q3;
    const int qt = bid % 7;
    const int h  = (bid / 7) % NH;
    const int b  = bid / (7 * NH);
    const int tid = threadIdx.x;
    const int lane = tid & 63, wv = tid >> 6;

    __shared__ __align__(16) unsigned short sK[64][72];
    __shared__ __align__(16) unsigned short sVT[64][72];
    __shared__ __align__(16) unsigned short sP[4][16][72];

    const int* xb = x + (size_t)b * T_;
    const unsigned short* qtab = ws + OFF_QTAB;
    const unsigned short* ktab = ws + OFF_KTAB;
    const unsigned short* vtab = ws + OFF_VTAB;

    const int qrow = qt * 64 + wv * 16 + (lane & 15);
    const int qtok = xb[qrow];
    const unsigned short* qbase =
        qtab + (size_t)qtok * NS + h * HD + (lane >> 4) * 8;
    bf16x8 qf0 = *(const bf16x8*)qbase;
    bf16x8 qf1 = *(const bf16x8*)(qbase + 32);

    f32x4 o[4];
    #pragma unroll
    for (int nf = 0; nf < 4; ++nf) o[nf] = (f32x4){0.f, 0.f, 0.f, 0.f};
    float lsum[4] = {0.f, 0.f, 0.f, 0.f};

    const int tk = tid >> 2;          // K-staging: token 0..63
    const int cc = (tid & 3) * 16;    // K-staging: d chunk
    const int vd = tid & 63;          // V-staging: d row
    const int vg = tid >> 6;          // V-staging: token group (16 tokens)

    // prefetch tile 0 into registers
    short8v kr0, kr1;
    unsigned short tv[16];
    {
        int tkn = xb[tk];
        const unsigned short* kset = ktab + (size_t)tkn * NS + h * HD + cc;
        kr0 = *(const short8v*)kset;
        kr1 = *(const short8v*)(kset + 8);
        #pragma unroll
        for (int j = 0; j < 16; ++j) {
            int t = xb[vg * 16 + j];
            tv[j] = vtab[(size_t)t * NS + h * HD + vd];
        }
    }

    for (int kv = 0; kv <= qt; ++kv) {
        __syncthreads();
        // write prefetched tile into LDS
        *(short8v*)&sK[tk][cc]           = kr0;
        *(short8v*)&sK[tk][cc + 8]       = kr1;
        *(short8v*)&sVT[vd][vg * 16]     = *(const short8v*)&tv[0];
        *(short8v*)&sVT[vd][vg * 16 + 8] = *(const short8v*)&tv[8];
        __syncthreads();

        // issue NEXT tile's loads now (after the barrier, so the compiler's
        // vmcnt(0)-before-s_barrier doesn't drain them): latency hides under
        // this tile's MFMA + exp work.
        if (kv < qt) {
            int base = (kv + 1) * 64;
            int tkn = xb[base + tk];
            const unsigned short* kset = ktab + (size_t)tkn * NS + h * HD + cc;
            kr0 = *(const short8v*)kset;
            kr1 = *(const short8v*)(kset + 8);
            #pragma unroll
            for (int j = 0; j < 16; ++j) {
                int t = xb[base + vg * 16 + j];
                tv[j] = vtab[(size_t)t * NS + h * HD + vd];
            }
        }

        // S = Q K^T  (16 q-rows x 64 kv-cols per wave); logits already *log2e
        f32x4 s[4];
        #pragma unroll
        for (int nf = 0; nf < 4; ++nf) s[nf] = (f32x4){0.f, 0.f, 0.f, 0.f};
        #pragma unroll
        for (int nf = 0; nf < 4; ++nf) {
            bf16x8 kb0 = *(const bf16x8*)&sK[nf * 16 + (lane & 15)][(lane >> 4) * 8];
            s[nf] = __builtin_amdgcn_mfma_f32_16x16x32_bf16(qf0, kb0, s[nf], 0, 0, 0);
            bf16x8 kb1 = *(const bf16x8*)&sK[nf * 16 + (lane & 15)][32 + (lane >> 4) * 8];
            s[nf] = __builtin_amdgcn_mfma_f32_16x16x32_bf16(qf1, kb1, s[nf], 0, 0, 0);
        }

        // no-max softmax: p = exp2(s); only diagonal tile needs the mask.
        // Tile-local row of this lane's r-th acc row is wv*16 + (lane>>4)*4 + r.
        if (kv == qt) {
            const int rloc = wv * 16 + (lane >> 4) * 4;   // tile-local row base
            const int cloc = lane & 15;
            #pragma unroll
            for (int nf = 0; nf < 4; ++nf)
                #pragma unroll
                for (int r = 0; r < 4; ++r) {
                    float sv = (cloc + nf * 16 > rloc + r) ? -1e30f : s[nf][r];
                    float p = exp2f(sv);
                    s[nf][r] = p;
                    lsum[r] += p;
                }
        } else {
            #pragma unroll
            for (int nf = 0; nf < 4; ++nf)
                #pragma unroll
                for (int r = 0; r < 4; ++r) {
                    float p = exp2f(s[nf][r]);
                    s[nf][r] = p;
                    lsum[r] += p;
                }
        }

        // P (D-layout) -> per-wave LDS -> A-frag layout
        #pragma unroll
        for (int nf = 0; nf < 4; ++nf)
            #pragma unroll
            for (int r = 0; r < 4; ++r)
                sP[wv][(lane >> 4) * 4 + r][nf * 16 + (lane & 15)] = f2bf(s[nf][r]);
        asm volatile("s_waitcnt lgkmcnt(0)" ::: "memory");

        bf16x8 pa0 = *(const bf16x8*)&sP[wv][lane & 15][(lane >> 4) * 8];
        bf16x8 pa1 = *(const bf16x8*)&sP[wv][lane & 15][32 + (lane >> 4) * 8];
        #pragma unroll
        for (int nf = 0; nf < 4; ++nf) {
            bf16x8 vb0 = *(const bf16x8*)&sVT[nf * 16 + (lane & 15)][(lane >> 4) * 8];
            o[nf] = __builtin_amdgcn_mfma_f32_16x16x32_bf16(pa0, vb0, o[nf], 0, 0, 0);
            bf16x8 vb1 = *(const bf16x8*)&sVT[nf * 16 + (lane & 15)][32 + (lane >> 4) * 8];
            o[nf] = __builtin_amdgcn_mfma_f32_16x16x32_bf16(pa1, vb1, o[nf], 0, 0, 0);
        }
    }

    // deferred l reduce (row spread over 16 lanes of same group)
    float inv[4];
    #pragma unroll
    for (int r = 0; r < 4; ++r) {
        float l = lsum[r];
        #pragma unroll
        for (int off = 1; off < 16; off <<= 1)
            l += __shfl_xor(l, off, 16);
        inv[r] = 1.0f / l;
    }

    #pragma unroll
    for (int nf = 0; nf < 4; ++nf) {
        int col = h * HD + nf * 16 + (lane & 15);
        #pragma unroll
        for (int r = 0; r < 4; ++r) {
            int rowg = qt * 64 + wv * 16 + (lane >> 4) * 4 + r;
            ctxb[((size_t)b * T_ + rowg) * NS + col] = f2bf(o[nf][r] * inv[r]);
        }
    }
}

// ---------------- kernel 3: out-projection (ctx bf16 in ws -> d_out) ------
// A-tile staged once; B register-direct from L2-hot Wo; no barriers in K-loop.
__global__ __launch_bounds__(256) void k_oproj(
    const unsigned short* __restrict__ ws, const float* __restrict__ bo,
    float* __restrict__ out)
{
    const int m0 = blockIdx.x * 64;
    const int tid = threadIdx.x;
    const int lane = tid & 63, wv = tid >> 6;

    __shared__ __align__(16) unsigned short sA[64][392];

    const unsigned short* ctxb = ws + OFF_CTX;

    {   // stage 64x384 ctx rows (bf16, straight copy)
        int r = tid >> 2, seg = tid & 3;
        const unsigned short* src = ctxb + (size_t)(m0 + r) * NS + seg * 96;
        unsigned short* dst = &sA[r][seg * 96];
        #pragma unroll
        for (int j = 0; j < 12; ++j)
            *(short8v*)(dst + j * 8) = *(const short8v*)(src + j * 8);
    }
    __syncthreads();

    f32x4 acc[4][6];
    #pragma unroll
    for (int i = 0; i < 4; ++i)
        #pragma unroll
        for (int j = 0; j < 6; ++j) acc[i][j] = (f32x4){0.f, 0.f, 0.f, 0.f};

    const int colA = lane & 15;
    const int kb = (lane >> 4) * 8;
    const unsigned short* wlane =
        ws + OFF_WO + (size_t)(wv * 96 + colA) * NS + kb;

    #pragma unroll 2
    for (int kc = 0; kc < 12; ++kc) {
        bf16x8 a[4], bfr[6];
        #pragma unroll
        for (int mf = 0; mf < 4; ++mf)
            a[mf] = *(const bf16x8*)&sA[mf * 16 + colA][kc * 32 + kb];
        #pragma unroll
        for (int nf = 0; nf < 6; ++nf)
            bfr[nf] = *(const bf16x8*)(wlane + (size_t)(nf * 16) * NS + kc * 32);
        #pragma unroll
        for (int mf = 0; mf < 4; ++mf)
            #pragma unroll
            for (int nf = 0; nf < 6; ++nf)
                acc[mf][nf] = __builtin_amdgcn_mfma_f32_16x16x32_bf16(
                    a[mf], bfr[nf], acc[mf][nf], 0, 0, 0);
    }

    const int r0 = (lane >> 4) * 4;
    #pragma unroll
    for (int nf = 0; nf < 6; ++nf) {
        int n = wv * 96 + nf * 16 + colA;
        float bias = bo[n];
        #pragma unroll
        for (int mf = 0; mf < 4; ++mf)
            #pragma unroll
            for (int r = 0; r < 4; ++r)
                out[(size_t)(m0 + mf * 16 + r0 + r) * NS + n] = acc[mf][nf][r] + bias;
    }
}

extern "C" void kernel_launch(void* const* d_in, const int* in_sizes, int n_in,
                              void* d_out, int out_size, void* d_ws, size_t ws_size,
                              hipStream_t stream) {
    const int*   x   = (const int*)d_in[0];
    const float* emb = (const float*)d_in[1];
    const float* Wq  = (const float*)d_in[2];
    const float* bq  = (const float*)d_in[3];
    const float* Wk  = (const float*)d_in[4];
    const float* Wv  = (const float*)d_in[5];
    const float* bv  = (const float*)d_in[6];
    const float* Wo  = (const float*)d_in[7];
    const float* bo  = (const float*)d_in[8];

    float* out   = (float*)d_out;
    float* out_k = out + NOUT;
    float* out_v = out + 2 * (size_t)NOUT;
    unsigned short* ws = (unsigned short*)d_ws;

    k_prep<<<dim3(144, 4), 256, 0, stream>>>(Wq, Wk, Wv, Wo, ws);
    k_table<<<dim3(313, 3), 256, 0, stream>>>(emb, ws, bq, bv, ws);
    k_attn_gather<<<dim3(NFUSE), 256, 0, stream>>>(x, ws, ws + OFF_CTX,
                                                   out_k, out_v);
    k_oproj<<<dim3(896), 256, 0, stream>>>(ws, bo, out);
}